// Round 1
// baseline (608.682 us; speedup 1.0000x reference)
//
#include <hip/hip_runtime.h>

typedef unsigned short u16;
typedef unsigned int   u32;

typedef __bf16 bf16x8 __attribute__((ext_vector_type(8)));
typedef float  f32x4  __attribute__((ext_vector_type(4)));

__device__ __forceinline__ float bf2f(u16 u) {
  union { u32 i; float f; } v; v.i = ((u32)u) << 16; return v.f;
}
__device__ __forceinline__ u16 f2bf(float f) {
  union { float f; u32 i; } v; v.f = f;
  u32 r = v.i + 0x7fffu + ((v.i >> 16) & 1u);   // RNE
  return (u16)(r >> 16);
}

__device__ __forceinline__ f32x4 mfma16(bf16x8 a, bf16x8 b, f32x4 c) {
  return __builtin_amdgcn_mfma_f32_16x16x32_bf16(a, b, c, 0, 0, 0);
}

#define GLOAD_LDS16(gsrc, ldst) \
  __builtin_amdgcn_global_load_lds((const __attribute__((address_space(1))) void*)(gsrc), \
                                   (__attribute__((address_space(3))) void*)(ldst), 16, 0, 0)

// ---------------- weight convert + transpose: Wt[n][k] = bf16(W[k][n]) ----------------
__global__ __launch_bounds__(256)
void wconv(const float* __restrict__ W, u16* __restrict__ Wt)
{
  __shared__ float tile[64][65];
  const int tx = threadIdx.x;           // 0..63
  const int ty = threadIdx.y;           // 0..3
  const int n0 = blockIdx.x * 64;
  const int k0 = blockIdx.y * 64;
#pragma unroll
  for (int j = 0; j < 16; ++j) {
    int k = ty + j * 4;
    tile[k][tx] = W[(size_t)(k0 + k) * 1024 + n0 + tx];
  }
  __syncthreads();
#pragma unroll
  for (int j = 0; j < 16; ++j) {
    int n = ty + j * 4;
    Wt[(size_t)(n0 + n) * 1024 + k0 + tx] = f2bf(tile[tx][n]);
  }
}

// ---------------- LayerNorm (row = 1024) -> bf16 ----------------
__global__ __launch_bounds__(256)
void ln_bf16(const float* __restrict__ in, const float* __restrict__ gw,
             const float* __restrict__ bw, u16* __restrict__ out)
{
  const int row = blockIdx.x;
  const int t = threadIdx.x;
  const float4 v = ((const float4*)(in + (size_t)row * 1024))[t];
  float s  = v.x + v.y + v.z + v.w;
  float sq = v.x*v.x + v.y*v.y + v.z*v.z + v.w*v.w;
#pragma unroll
  for (int o = 32; o >= 1; o >>= 1) {
    s  += __shfl_xor(s, o);
    sq += __shfl_xor(sq, o);
  }
  __shared__ float red[8];
  const int wv = t >> 6;
  if ((t & 63) == 0) { red[wv] = s; red[4 + wv] = sq; }
  __syncthreads();
  s  = red[0] + red[1] + red[2] + red[3];
  sq = red[4] + red[5] + red[6] + red[7];
  const float mean = s * (1.f / 1024.f);
  const float var  = sq * (1.f / 1024.f) - mean * mean;
  const float rstd = rsqrtf(var + 1e-6f);
  const float4 g4 = ((const float4*)gw)[t];
  const float4 b4 = ((const float4*)bw)[t];
  u32 lo = (u32)f2bf((v.x - mean) * rstd * g4.x + b4.x) |
           ((u32)f2bf((v.y - mean) * rstd * g4.y + b4.y) << 16);
  u32 hi = (u32)f2bf((v.z - mean) * rstd * g4.z + b4.z) |
           ((u32)f2bf((v.w - mean) * rstd * g4.w + b4.w) << 16);
  uint2 w; w.x = lo; w.y = hi;
  ((uint2*)(out + (size_t)row * 1024))[t] = w;
}

// ---------------- GEMM: C[M,N] = A[M,K](bf16) @ Bt[N,K](bf16)^T + bias ----------------
// MODE 0: bf16 row-major   MODE 1: bf16 [B,H,L,HD]   MODE 2: bf16 [B,H,HD,L]
// MODE 3: f32 row-major (+res if res!=null)
template<int MODE>
__global__ __launch_bounds__(256)
void gemm_bt(const u16* __restrict__ A, const u16* __restrict__ Bt,
             const float* __restrict__ bias1, float b1s, const float* __restrict__ bias2,
             void* __restrict__ outv, const float* __restrict__ res,
             int M, int N, int K)
{
  __shared__ u16 As[128 * 64];
  __shared__ u16 Bs[128 * 64];
  const int t    = threadIdx.x;
  const int lane = t & 63;
  const int wave = t >> 6;
  const int qi   = lane & 15;
  const int g    = lane >> 4;
  const int row0 = blockIdx.y * 128;
  const int col0 = blockIdx.x * 128;
  const int wrow = (wave >> 1) * 64;
  const int wcol = (wave & 1) * 64;

  f32x4 acc[4][4] = {};

  const int srow  = lane >> 3;        // 0..7 within 8-row chunk
  const int skseg = (lane & 7) * 8;   // k element offset within BK

  for (int kt = 0; kt < K; kt += 64) {
    __syncthreads();
#pragma unroll
    for (int i = 0; i < 8; ++i) {
      int chunk = wave * 8 + i;       // 0..31, wave-uniform
      int c = chunk & 15;
      int r = c * 8 + srow;
      if (chunk < 16) {
        GLOAD_LDS16(A  + (size_t)(row0 + r) * K + kt + skseg, As + c * 512);
      } else {
        GLOAD_LDS16(Bt + (size_t)(col0 + r) * K + kt + skseg, Bs + c * 512);
      }
    }
    __syncthreads();
#pragma unroll
    for (int kk = 0; kk < 2; ++kk) {
      bf16x8 af[4], bfv[4];
#pragma unroll
      for (int m = 0; m < 4; ++m)
        af[m] = *(const bf16x8*)(As + (wrow + m * 16 + qi) * 64 + kk * 32 + g * 8);
#pragma unroll
      for (int n = 0; n < 4; ++n)
        bfv[n] = *(const bf16x8*)(Bs + (wcol + n * 16 + qi) * 64 + kk * 32 + g * 8);
#pragma unroll
      for (int m = 0; m < 4; ++m)
#pragma unroll
        for (int n = 0; n < 4; ++n)
          acc[m][n] = mfma16(af[m], bfv[n], acc[m][n]);
    }
  }

#pragma unroll
  for (int n = 0; n < 4; ++n) {
    int col = col0 + wcol + n * 16 + qi;
    float badd = 0.f;
    if (bias1) badd = bias1[col] * b1s;
    if (bias2) badd += bias2[col];
#pragma unroll
    for (int m = 0; m < 4; ++m) {
#pragma unroll
      for (int j = 0; j < 4; ++j) {
        int row = row0 + wrow + m * 16 + g * 4 + j;
        float v = acc[m][n][j] + badd;
        if constexpr (MODE == 0) {
          ((u16*)outv)[(size_t)row * N + col] = f2bf(v);
        } else if constexpr (MODE == 1) {
          int b = row >> 9, l = row & 511, h = col >> 6, hd = col & 63;
          ((u16*)outv)[(((size_t)(b * 16 + h) * 512) + l) * 64 + hd] = f2bf(v);
        } else if constexpr (MODE == 2) {
          int b = row >> 9, l = row & 511, h = col >> 6, hd = col & 63;
          ((u16*)outv)[(((size_t)(b * 16 + h) * 64) + hd) * 512 + l] = f2bf(v);
        } else {
          float o = v;
          if (res) o += res[(size_t)row * N + col];
          ((float*)outv)[(size_t)row * N + col] = o;
        }
      }
    }
  }
}

// ---------------- fused flash attention ----------------
// Q,K: [B,H,L,64] bf16; Vt: [B,H,64,T] bf16; ctx: [B,L,1024] bf16 (merged)
__global__ __launch_bounds__(256)
void attn_fused(const u16* __restrict__ Q, const u16* __restrict__ Kh,
                const u16* __restrict__ Vt, const int* __restrict__ qmask,
                const int* __restrict__ kmask, u16* __restrict__ ctx)
{
  const int T = 512, L = 512;
  const int lane = threadIdx.x & 63;
  const int wave = threadIdx.x >> 6;
  const int qi = lane & 15;
  const int g  = lane >> 4;
  const int bh = blockIdx.y;
  const int b  = bh >> 4;
  const int h  = bh & 15;
  const int q0 = blockIdx.x * 64 + wave * 16;

  __shared__ u16 Plds[4][16 * 56];   // per-wave P^T bounce, stride 56 (16B-aligned, conflict-light)
  u16* Pl = Plds[wave];

  const size_t qoff = ((size_t)bh * L + q0 + qi) * 64;
  const bf16x8 qf0 = *(const bf16x8*)(Q + qoff + g * 8);
  const bf16x8 qf1 = *(const bf16x8*)(Q + qoff + 32 + g * 8);

  const float qmv = (float)qmask[b * L + q0 + qi];
  float mrun = -__builtin_inff(), lrun = 0.f;
  f32x4 of[4] = {};

  for (int kb = 0; kb < T; kb += 32) {
    f32x4 st[2] = {};
#pragma unroll
    for (int s = 0; s < 2; ++s) {
      const size_t koff = ((size_t)bh * T + kb + s * 16 + qi) * 64;
      bf16x8 ka0 = *(const bf16x8*)(Kh + koff + g * 8);
      bf16x8 ka1 = *(const bf16x8*)(Kh + koff + 32 + g * 8);
      st[s] = mfma16(ka0, qf0, st[s]);   // St[key, q]
      st[s] = mfma16(ka1, qf1, st[s]);
    }
    float pv[8];
    float tmax = -__builtin_inff();
#pragma unroll
    for (int s = 0; s < 2; ++s)
#pragma unroll
      for (int j = 0; j < 4; ++j) {
        int key = kb + s * 16 + g * 4 + j;
        float km = (float)kmask[b * T + key];
        float sv = st[s][j] * 0.125f + (1.f - qmv * km) * (-1e30f);
        pv[s * 4 + j] = sv;
        tmax = fmaxf(tmax, sv);
      }
    tmax = fmaxf(tmax, __shfl_xor(tmax, 16));
    tmax = fmaxf(tmax, __shfl_xor(tmax, 32));
    const float mnew = fmaxf(mrun, tmax);
    const float corr = expf(mrun - mnew);
    float tsum = 0.f;
#pragma unroll
    for (int i = 0; i < 8; ++i) {
      float p = expf(pv[i] - mnew);
      pv[i] = p;
      tsum += p;
    }
    tsum += __shfl_xor(tsum, 16);
    tsum += __shfl_xor(tsum, 32);
    lrun = lrun * corr + tsum;
    mrun = mnew;
    // write P^T -> LDS as [q][key_local]
#pragma unroll
    for (int s = 0; s < 2; ++s) {
      u32 lo = (u32)f2bf(pv[s * 4 + 0]) | ((u32)f2bf(pv[s * 4 + 1]) << 16);
      u32 hi = (u32)f2bf(pv[s * 4 + 2]) | ((u32)f2bf(pv[s * 4 + 3]) << 16);
      uint2 w; w.x = lo; w.y = hi;
      *(uint2*)(Pl + qi * 56 + s * 16 + g * 4) = w;
    }
    __syncthreads();
    float cj[4];
#pragma unroll
    for (int j = 0; j < 4; ++j) cj[j] = __shfl(corr, g * 4 + j);
    const bf16x8 pa = *(const bf16x8*)(Pl + qi * 56 + g * 8);
#pragma unroll
    for (int nf = 0; nf < 4; ++nf) {
      const size_t voff = ((size_t)bh * 64 + nf * 16 + qi) * (size_t)T + kb + g * 8;
      bf16x8 vb = *(const bf16x8*)(Vt + voff);
      f32x4 o = of[nf];
#pragma unroll
      for (int j = 0; j < 4; ++j) o[j] *= cj[j];
      of[nf] = mfma16(pa, vb, o);
    }
    __syncthreads();
  }
  const float linv = 1.f / lrun;
  float lj[4];
#pragma unroll
  for (int j = 0; j < 4; ++j) lj[j] = __shfl(linv, g * 4 + j);
#pragma unroll
  for (int nf = 0; nf < 4; ++nf) {
    int col = h * 64 + nf * 16 + qi;
#pragma unroll
    for (int j = 0; j < 4; ++j) {
      int row = q0 + g * 4 + j;
      ctx[((size_t)b * L + row) * 1024 + col] = f2bf(of[nf][j] * lj[j]);
    }
  }
}

// ---------------- elementwise ----------------
__global__ __launch_bounds__(256)
void ew_gated(const u16* __restrict__ sg, const u16* __restrict__ xv,
              const u16* __restrict__ xg, const u16* __restrict__ sv,
              u16* __restrict__ out, int n)
{
  int i = (blockIdx.x * 256 + threadIdx.x) * 8;
  if (i >= n) return;
  uint4 A = *(const uint4*)(sg + i);
  uint4 B = *(const uint4*)(xv + i);
  uint4 C = *(const uint4*)(xg + i);
  uint4 D = *(const uint4*)(sv + i);
  const u32* pa = (const u32*)&A; const u32* pb = (const u32*)&B;
  const u32* pc = (const u32*)&C; const u32* pd = (const u32*)&D;
  u32 r[4];
#pragma unroll
  for (int k = 0; k < 4; ++k) {
    float a0 = bf2f((u16)(pa[k] & 0xffffu)), a1 = bf2f((u16)(pa[k] >> 16));
    float b0 = bf2f((u16)(pb[k] & 0xffffu)), b1 = bf2f((u16)(pb[k] >> 16));
    float c0 = bf2f((u16)(pc[k] & 0xffffu)), c1 = bf2f((u16)(pc[k] >> 16));
    float d0 = bf2f((u16)(pd[k] & 0xffffu)), d1 = bf2f((u16)(pd[k] >> 16));
    r[k] = (u32)f2bf(a0 * b0 + c0 * d0) | ((u32)f2bf(a1 * b1 + c1 * d1) << 16);
  }
  *(uint4*)(out + i) = *(uint4*)r;
}

__global__ __launch_bounds__(256)
void ew_add(const u16* __restrict__ a, const u16* __restrict__ b,
            u16* __restrict__ out, int n)
{
  int i = (blockIdx.x * 256 + threadIdx.x) * 8;
  if (i >= n) return;
  uint4 A = *(const uint4*)(a + i);
  uint4 B = *(const uint4*)(b + i);
  const u32* pa = (const u32*)&A; const u32* pb = (const u32*)&B;
  u32 r[4];
#pragma unroll
  for (int k = 0; k < 4; ++k) {
    float a0 = bf2f((u16)(pa[k] & 0xffffu)) + bf2f((u16)(pb[k] & 0xffffu));
    float a1 = bf2f((u16)(pa[k] >> 16))     + bf2f((u16)(pb[k] >> 16));
    r[k] = (u32)f2bf(a0) | ((u32)f2bf(a1) << 16);
  }
  *(uint4*)(out + i) = *(uint4*)r;
}

__global__ __launch_bounds__(256)
void ew_attnout(const float* __restrict__ sc, const float* __restrict__ vl,
                const int* __restrict__ fm, u16* __restrict__ out, int n)
{
  int i = (blockIdx.x * 256 + threadIdx.x) * 4;
  if (i >= n) return;
  float4 s4 = *(const float4*)(sc + i);
  float4 v4 = *(const float4*)(vl + i);
  int row = i >> 10;
  float neg = (1.f - (float)fm[row]) * (-1e30f);
  const float* sp = &s4.x; const float* vp = &v4.x;
  float r[4];
#pragma unroll
  for (int k = 0; k < 4; ++k) {
    float x = sp[k] + neg;
    r[k] = (1.f / (1.f + expf(-x))) * vp[k];
  }
  u32 lo = (u32)f2bf(r[0]) | ((u32)f2bf(r[1]) << 16);
  u32 hi = (u32)f2bf(r[2]) | ((u32)f2bf(r[3]) << 16);
  uint2 w; w.x = lo; w.y = hi;
  *(uint2*)(out + i) = w;
}

// ---------------- driver ----------------
extern "C" void kernel_launch(void* const* d_in, const int* in_sizes, int n_in,
                              void* d_out, int out_size, void* d_ws, size_t ws_size,
                              hipStream_t stream)
{
  (void)in_sizes; (void)n_in; (void)out_size; (void)ws_size;
  const float* from = (const float*)d_in[0];
  const float* to_t = (const float*)d_in[1];
  const float* ln1g = (const float*)d_in[2];
  const float* ln1b = (const float*)d_in[3];
  const float* lntg = (const float*)d_in[4];
  const float* lntb = (const float*)d_in[5];
  const float* ln2g = (const float*)d_in[6];
  const float* ln2b = (const float*)d_in[7];
  const int* fmask = (const int*)d_in[38];
  const int* tmask = (const int*)d_in[39];

  char* ws = (char*)d_ws;
  const size_t MB = 1ull << 20;
  auto WT = [&](int i) { return (u16*)(ws + (size_t)i * 2 * MB); };   // 0..28MB
  u16*   xbf    = (u16*)(ws + 28 * MB);
  u16*   tbf    = (u16*)(ws + 36 * MB);
  u16*   qh     = (u16*)(ws + 44 * MB);
  u16*   fkh    = (u16*)(ws + 52 * MB);
  u16*   fvt    = (u16*)(ws + 60 * MB);
  u16*   tkh    = (u16*)(ws + 68 * MB);
  u16*   tvt    = (u16*)(ws + 76 * MB);
  u16*   sctx   = (u16*)(ws + 84 * MB);
  u16*   xctx   = (u16*)(ws + 92 * MB);
  // reuse (temporally disjoint):
  u16*   svb    = (u16*)(ws + 44 * MB);
  u16*   xvb    = (u16*)(ws + 52 * MB);
  u16*   sgb    = (u16*)(ws + 60 * MB);
  u16*   xgb    = (u16*)(ws + 68 * MB);
  u16*   gated  = (u16*)(ws + 76 * MB);
  u16*   guided = (u16*)(ws + 84 * MB);
  u16*   sumbf  = (u16*)(ws + 92 * MB);
  float* scores = (float*)(ws + 44 * MB);
  float* values = (float*)(ws + 60 * MB);
  u16*   abf    = (u16*)(ws + 76 * MB);
  float* resid  = (float*)(ws + 84 * MB);
  u16*   lnr    = (u16*)(ws + 36 * MB);

  const int widx[14] = {8, 10, 12, 14, 16, 18, 20, 22, 24, 26, 28, 31, 34, 36};
  for (int i = 0; i < 14; ++i)
    wconv<<<dim3(16, 16), dim3(64, 4), 0, stream>>>((const float*)d_in[widx[i]], WT(i));

  ln_bf16<<<4096, 256, 0, stream>>>(from, ln1g, ln1b, xbf);
  ln_bf16<<<4096, 256, 0, stream>>>(to_t, lntg, lntb, tbf);

  dim3 ggrid(8, 32), gblk(256);
  const int M = 4096, N = 1024, Kd = 1024;
  gemm_bt<1><<<ggrid, gblk, 0, stream>>>(xbf, WT(0), (const float*)d_in[9],  1.f, nullptr, qh,  nullptr, M, N, Kd);
  gemm_bt<1><<<ggrid, gblk, 0, stream>>>(xbf, WT(1), (const float*)d_in[11], 1.f, nullptr, fkh, nullptr, M, N, Kd);
  gemm_bt<2><<<ggrid, gblk, 0, stream>>>(xbf, WT(2), (const float*)d_in[13], 1.f, nullptr, fvt, nullptr, M, N, Kd);
  gemm_bt<1><<<ggrid, gblk, 0, stream>>>(tbf, WT(3), (const float*)d_in[15], 1.f, nullptr, tkh, nullptr, M, N, Kd);
  gemm_bt<2><<<ggrid, gblk, 0, stream>>>(tbf, WT(4), (const float*)d_in[17], 1.f, nullptr, tvt, nullptr, M, N, Kd);

  attn_fused<<<dim3(8, 128), 256, 0, stream>>>(qh, fkh, fvt, fmask, fmask, sctx);
  attn_fused<<<dim3(8, 128), 256, 0, stream>>>(qh, tkh, tvt, fmask, tmask, xctx);

  gemm_bt<0><<<ggrid, gblk, 0, stream>>>(sctx, WT(5), (const float*)d_in[19], 1.f, nullptr, svb, nullptr, M, N, Kd);
  gemm_bt<0><<<ggrid, gblk, 0, stream>>>(xctx, WT(6), (const float*)d_in[21], 1.f, nullptr, xvb, nullptr, M, N, Kd);
  gemm_bt<0><<<ggrid, gblk, 0, stream>>>(svb,  WT(7), (const float*)d_in[23], 1.f, nullptr, sgb, nullptr, M, N, Kd);
  gemm_bt<0><<<ggrid, gblk, 0, stream>>>(xvb,  WT(8), (const float*)d_in[25], 1.f, nullptr, xgb, nullptr, M, N, Kd);

  const int n = 4096 * 1024;
  ew_gated<<<n / (256 * 8), 256, 0, stream>>>(sgb, xvb, xgb, svb, gated, n);
  gemm_bt<0><<<ggrid, gblk, 0, stream>>>(gated, WT(9), (const float*)d_in[27], 1.f, nullptr, guided, nullptr, M, N, Kd);
  ew_add<<<n / (256 * 8), 256, 0, stream>>>(xbf, guided, sumbf, n);
  gemm_bt<3><<<ggrid, gblk, 0, stream>>>(sumbf, WT(10), (const float*)d_in[29], 2.f, (const float*)d_in[30], scores, nullptr, M, N, Kd);
  gemm_bt<3><<<ggrid, gblk, 0, stream>>>(sumbf, WT(11), (const float*)d_in[32], 2.f, (const float*)d_in[33], values, nullptr, M, N, Kd);
  ew_attnout<<<n / (256 * 4), 256, 0, stream>>>(scores, values, fmask, abf, n);
  gemm_bt<3><<<ggrid, gblk, 0, stream>>>(abf, WT(12), (const float*)d_in[35], 1.f, nullptr, resid, from, M, N, Kd);
  ln_bf16<<<4096, 256, 0, stream>>>(resid, ln2g, ln2b, lnr);
  gemm_bt<3><<<ggrid, gblk, 0, stream>>>(lnr, WT(13), (const float*)d_in[37], 1.f, nullptr, (float*)d_out, resid, M, N, Kd);
}

// Round 2
// 558.492 us; speedup vs baseline: 1.0899x; 1.0899x over previous
//
#include <hip/hip_runtime.h>

typedef unsigned short u16;
typedef unsigned int   u32;

typedef __bf16 bf16x8 __attribute__((ext_vector_type(8)));
typedef float  f32x4  __attribute__((ext_vector_type(4)));

__device__ __forceinline__ float bf2f(u16 u) {
  union { u32 i; float f; } v; v.i = ((u32)u) << 16; return v.f;
}
__device__ __forceinline__ u16 f2bf(float f) {
  union { float f; u32 i; } v; v.f = f;
  u32 r = v.i + 0x7fffu + ((v.i >> 16) & 1u);   // RNE
  return (u16)(r >> 16);
}
__device__ __forceinline__ u32 cvtpk(float a, float b) {
  u32 r;
  asm("v_cvt_pk_bf16_f32 %0, %1, %2" : "=v"(r) : "v"(a), "v"(b));
  return r;
}

__device__ __forceinline__ f32x4 mfma16(bf16x8 a, bf16x8 b, f32x4 c) {
  return __builtin_amdgcn_mfma_f32_16x16x32_bf16(a, b, c, 0, 0, 0);
}

#define GLOAD_LDS16(gsrc, ldst) \
  __builtin_amdgcn_global_load_lds((const __attribute__((address_space(1))) void*)(gsrc), \
                                   (__attribute__((address_space(3))) void*)(ldst), 16, 0, 0)

// 0.125 * log2(e): folded into Q so softmax can use exp2
#define QSCALE 0.18033688011112042f

// ---------------- merged weight convert: Wt[n][k] = bf16(W[k][n]) ----------------
struct W14 { const float* p[14]; };

__global__ __launch_bounds__(256)
void wconv(W14 srcs, u16* __restrict__ base)
{
  __shared__ float tile[64][65];
  const int tx = threadIdx.x;           // 0..63
  const int ty = threadIdx.y;           // 0..3
  const int n0 = blockIdx.x * 64;
  const int k0 = blockIdx.y * 64;
  const float* W = srcs.p[blockIdx.z];
  u16* Wt = base + ((size_t)blockIdx.z << 20);
#pragma unroll
  for (int j = 0; j < 16; ++j) {
    int k = ty + j * 4;
    tile[k][tx] = W[(size_t)(k0 + k) * 1024 + n0 + tx];
  }
  __syncthreads();
#pragma unroll
  for (int j = 0; j < 16; ++j) {
    int n = ty + j * 4;
    Wt[(size_t)(n0 + n) * 1024 + k0 + tx] = f2bf(tile[tx][n]);
  }
}

// ---------------- mask -> additive float ----------------
__global__ __launch_bounds__(256)
void mk_maskf(const int* __restrict__ fm, const int* __restrict__ tm,
              float* __restrict__ fa, float* __restrict__ ta)
{
  int i = blockIdx.x * 256 + threadIdx.x;   // grid 16 * 256 = 4096
  fa[i] = fm[i] ? 0.f : -1e30f;
  ta[i] = tm[i] ? 0.f : -1e30f;
}

// ---------------- LayerNorm (row = 1024) -> bf16, dual source ----------------
__global__ __launch_bounds__(256)
void ln_bf16(const float* __restrict__ in0, const float* __restrict__ g0,
             const float* __restrict__ b0, u16* __restrict__ out0,
             const float* __restrict__ in1, const float* __restrict__ g1,
             const float* __restrict__ b1, u16* __restrict__ out1, int split)
{
  int row = blockIdx.x;
  const float *in, *gw, *bw; u16* out;
  if (row < split) { in = in0; gw = g0; bw = b0; out = out0; }
  else             { in = in1; gw = g1; bw = b1; out = out1; row -= split; }
  const int t = threadIdx.x;
  const float4 v = ((const float4*)(in + (size_t)row * 1024))[t];
  float s  = v.x + v.y + v.z + v.w;
  float sq = v.x*v.x + v.y*v.y + v.z*v.z + v.w*v.w;
#pragma unroll
  for (int o = 32; o >= 1; o >>= 1) {
    s  += __shfl_xor(s, o);
    sq += __shfl_xor(sq, o);
  }
  __shared__ float red[8];
  const int wv = t >> 6;
  if ((t & 63) == 0) { red[wv] = s; red[4 + wv] = sq; }
  __syncthreads();
  s  = red[0] + red[1] + red[2] + red[3];
  sq = red[4] + red[5] + red[6] + red[7];
  const float mean = s * (1.f / 1024.f);
  const float var  = sq * (1.f / 1024.f) - mean * mean;
  const float rstd = rsqrtf(var + 1e-6f);
  const float4 g4 = ((const float4*)gw)[t];
  const float4 b4 = ((const float4*)bw)[t];
  uint2 w;
  w.x = cvtpk((v.x - mean) * rstd * g4.x + b4.x, (v.y - mean) * rstd * g4.y + b4.y);
  w.y = cvtpk((v.z - mean) * rstd * g4.z + b4.z, (v.w - mean) * rstd * g4.w + b4.w);
  ((uint2*)(out + (size_t)row * 1024))[t] = w;
}

// ---------------- GEMM: C = A[M,K](bf16) @ Bt[N,K](bf16)^T, multi-chunk / z-batched ----
// mode 0: bf16 row-major; 1: bf16 [B,H,L,HD]; 2: bf16 [B,H,HD,L];
// 3: f32 (+f32 res); 4: bf16 (+bf16 res)
struct GOut  { void* ptr; const float* bias; const float* bias2; const void* res;
               float bscale; float oscale; int mode; };
struct GProb { const u16* A; const u16* Bt; GOut od[3]; };

__global__ __launch_bounds__(256)
void gemm_bt(GProb P0, GProb P1, int M, int K)
{
  const GProb pr = blockIdx.z ? P1 : P0;
  __shared__ u16 As[128 * 64];
  __shared__ u16 Bs[128 * 64];
  const int t    = threadIdx.x;
  const int lane = t & 63;
  const int wave = t >> 6;
  const int qi   = lane & 15;
  const int g    = lane >> 4;
  const int row0 = blockIdx.y * 128;
  const int col0 = blockIdx.x * 128;           // global Bt row
  const int wrow = (wave >> 1) * 64;
  const int wcol = (wave & 1) * 64;

  f32x4 acc[4][4] = {};

  const int srow  = lane >> 3;
  const int skseg = (lane & 7) * 8;
  const u16* A  = pr.A;
  const u16* Bt = pr.Bt;

  for (int kt = 0; kt < K; kt += 64) {
    __syncthreads();
#pragma unroll
    for (int i = 0; i < 8; ++i) {
      int chunk = wave * 8 + i;
      int c = chunk & 15;
      int r = c * 8 + srow;
      if (chunk < 16) {
        GLOAD_LDS16(A  + (size_t)(row0 + r) * K + kt + skseg, As + c * 512);
      } else {
        GLOAD_LDS16(Bt + (size_t)(col0 + r) * K + kt + skseg, Bs + c * 512);
      }
    }
    __syncthreads();
#pragma unroll
    for (int kk = 0; kk < 2; ++kk) {
      bf16x8 af[4], bfv[4];
#pragma unroll
      for (int m = 0; m < 4; ++m)
        af[m] = *(const bf16x8*)(As + (wrow + m * 16 + qi) * 64 + kk * 32 + g * 8);
#pragma unroll
      for (int n = 0; n < 4; ++n)
        bfv[n] = *(const bf16x8*)(Bs + (wcol + n * 16 + qi) * 64 + kk * 32 + g * 8);
#pragma unroll
      for (int m = 0; m < 4; ++m)
#pragma unroll
        for (int n = 0; n < 4; ++n)
          acc[m][n] = mfma16(af[m], bfv[n], acc[m][n]);
    }
  }

  const GOut od = pr.od[blockIdx.x >> 3];
  const int cbase = (blockIdx.x & 7) * 128 + wcol;
#pragma unroll
  for (int n = 0; n < 4; ++n) {
    int coll = cbase + n * 16 + qi;
    float badd = 0.f;
    if (od.bias)  badd = od.bias[coll] * od.bscale;
    if (od.bias2) badd += od.bias2[coll];
#pragma unroll
    for (int m = 0; m < 4; ++m) {
#pragma unroll
      for (int j = 0; j < 4; ++j) {
        int row = row0 + wrow + m * 16 + g * 4 + j;
        float v = (acc[m][n][j] + badd) * od.oscale;
        if (od.mode == 0) {
          ((u16*)od.ptr)[(size_t)row * 1024 + coll] = f2bf(v);
        } else if (od.mode == 1) {
          int bb = row >> 9, l = row & 511, hh = coll >> 6, hd = coll & 63;
          ((u16*)od.ptr)[(((size_t)(bb * 16 + hh) * 512) + l) * 64 + hd] = f2bf(v);
        } else if (od.mode == 2) {
          int bb = row >> 9, l = row & 511, hh = coll >> 6, hd = coll & 63;
          ((u16*)od.ptr)[(((size_t)(bb * 16 + hh) * 64) + hd) * 512 + l] = f2bf(v);
        } else if (od.mode == 3) {
          float o = v;
          if (od.res) o += ((const float*)od.res)[(size_t)row * 1024 + coll];
          ((float*)od.ptr)[(size_t)row * 1024 + coll] = o;
        } else {
          float o = v + bf2f(((const u16*)od.res)[(size_t)row * 1024 + coll]);
          ((u16*)od.ptr)[(size_t)row * 1024 + coll] = f2bf(o);
        }
      }
    }
  }
}

// ---------------- fused flash attention ----------------
// Q (pre-scaled by QSCALE), K: [B,H,L,64] bf16; Vt: [B,H,64,T] bf16
// kadd: [B,T] float additive mask (0 or -1e30, pre-scaled base-2 domain trivially ok)
__global__ __launch_bounds__(256)
void attn_fused(const u16* __restrict__ Q, const u16* __restrict__ Kh,
                const u16* __restrict__ Vt, const int* __restrict__ qmask,
                const float* __restrict__ kadd, u16* __restrict__ ctx)
{
  const int T = 512, L = 512;
  const int lane = threadIdx.x & 63;
  const int wave = threadIdx.x >> 6;
  const int qi = lane & 15;
  const int g  = lane >> 4;
  // XCD-bijective remap: each XCD owns 16 whole bh (K/V set = 2MB, L2-resident)
  const int bid  = blockIdx.x;              // 0..1023
  const int iw   = bid >> 3;
  const int bh   = (bid & 7) * 16 + (iw & 15);
  const int qblk = iw >> 4;
  const int b  = bh >> 4;
  const int h  = bh & 15;
  const int q0 = qblk * 64 + wave * 16;

  __shared__ u16 Plds[4][16 * 72];          // per-wave P^T bounce, NO barriers needed
  u16* Pl = Plds[wave];

  const size_t qoff = ((size_t)bh * L + q0 + qi) * 64;
  const bf16x8 qf0 = *(const bf16x8*)(Q + qoff + g * 8);
  const bf16x8 qf1 = *(const bf16x8*)(Q + qoff + 32 + g * 8);

  const float qmv = (float)qmask[b * L + q0 + qi];
  const float* kaddb = kadd + b * T;
  float mrun = -3.0e38f, lrun = 0.f;
  f32x4 of[4] = {};

  for (int kb = 0; kb < T; kb += 64) {
    f32x4 st[4] = {};
#pragma unroll
    for (int s = 0; s < 4; ++s) {
      const size_t koff = ((size_t)bh * T + kb + s * 16 + qi) * 64;
      bf16x8 ka0 = *(const bf16x8*)(Kh + koff + g * 8);
      bf16x8 ka1 = *(const bf16x8*)(Kh + koff + 32 + g * 8);
      st[s] = mfma16(ka0, qf0, st[s]);      // St[key, q]
      st[s] = mfma16(ka1, qf1, st[s]);
    }
    float pv[16];
    float tmax = -3.0e38f;
#pragma unroll
    for (int s = 0; s < 4; ++s) {
      float4 kv = *(const float4*)(kaddb + kb + s * 16 + g * 4);
      const float* kp = &kv.x;
#pragma unroll
      for (int j = 0; j < 4; ++j) {
        float sv = (st[s][j] + kp[j]) * qmv;   // qmv==0 -> uniform row (matches ref)
        pv[s * 4 + j] = sv;
        tmax = fmaxf(tmax, sv);
      }
    }
    tmax = fmaxf(tmax, __shfl_xor(tmax, 16));
    tmax = fmaxf(tmax, __shfl_xor(tmax, 32));
    const float mnew = fmaxf(mrun, tmax);
    const float corr = exp2f(mrun - mnew);
    float tsum = 0.f;
#pragma unroll
    for (int i = 0; i < 16; ++i) {
      float p = exp2f(pv[i] - mnew);
      pv[i] = p;
      tsum += p;
    }
    tsum += __shfl_xor(tsum, 16);
    tsum += __shfl_xor(tsum, 32);
    lrun = lrun * corr + tsum;
    mrun = mnew;
    // write P^T -> per-wave LDS as [q][key_local]
#pragma unroll
    for (int s = 0; s < 4; ++s) {
      uint2 w;
      w.x = cvtpk(pv[s * 4 + 0], pv[s * 4 + 1]);
      w.y = cvtpk(pv[s * 4 + 2], pv[s * 4 + 3]);
      *(uint2*)(Pl + qi * 72 + s * 16 + g * 4) = w;
    }
    float cj[4];
#pragma unroll
    for (int j = 0; j < 4; ++j) cj[j] = __shfl(corr, g * 4 + j);
    const bf16x8 pa0 = *(const bf16x8*)(Pl + qi * 72 + g * 8);
    const bf16x8 pa1 = *(const bf16x8*)(Pl + qi * 72 + 32 + g * 8);
#pragma unroll
    for (int nf = 0; nf < 4; ++nf) {
      const size_t voff = ((size_t)bh * 64 + nf * 16 + qi) * (size_t)T + kb + g * 8;
      bf16x8 vb0 = *(const bf16x8*)(Vt + voff);
      bf16x8 vb1 = *(const bf16x8*)(Vt + voff + 32);
      f32x4 o = of[nf];
#pragma unroll
      for (int j = 0; j < 4; ++j) o[j] *= cj[j];
      o = mfma16(pa0, vb0, o);
      of[nf] = mfma16(pa1, vb1, o);
    }
  }
  const float linv = 1.f / lrun;
  float lj[4];
#pragma unroll
  for (int j = 0; j < 4; ++j) lj[j] = __shfl(linv, g * 4 + j);
#pragma unroll
  for (int nf = 0; nf < 4; ++nf) {
    int col = h * 64 + nf * 16 + qi;
#pragma unroll
    for (int j = 0; j < 4; ++j) {
      int row = q0 + g * 4 + j;
      ctx[((size_t)b * L + row) * 1024 + col] = f2bf(of[nf][j] * lj[j]);
    }
  }
}

// ---------------- elementwise ----------------
__global__ __launch_bounds__(256)
void ew_gated(const u16* __restrict__ sg, const u16* __restrict__ xv,
              const u16* __restrict__ xg, const u16* __restrict__ sv,
              u16* __restrict__ out, int n)
{
  int i = (blockIdx.x * 256 + threadIdx.x) * 8;
  if (i >= n) return;
  uint4 A = *(const uint4*)(sg + i);
  uint4 B = *(const uint4*)(xv + i);
  uint4 C = *(const uint4*)(xg + i);
  uint4 D = *(const uint4*)(sv + i);
  const u32* pa = (const u32*)&A; const u32* pb = (const u32*)&B;
  const u32* pc = (const u32*)&C; const u32* pd = (const u32*)&D;
  u32 r[4];
#pragma unroll
  for (int k = 0; k < 4; ++k) {
    float a0 = bf2f((u16)(pa[k] & 0xffffu)), a1 = bf2f((u16)(pa[k] >> 16));
    float b0 = bf2f((u16)(pb[k] & 0xffffu)), b1 = bf2f((u16)(pb[k] >> 16));
    float c0 = bf2f((u16)(pc[k] & 0xffffu)), c1 = bf2f((u16)(pc[k] >> 16));
    float d0 = bf2f((u16)(pd[k] & 0xffffu)), d1 = bf2f((u16)(pd[k] >> 16));
    r[k] = cvtpk(a0 * b0 + c0 * d0, a1 * b1 + c1 * d1);
  }
  *(uint4*)(out + i) = *(uint4*)r;
}

__global__ __launch_bounds__(256)
void ew_attnout(const float* __restrict__ sc, const float* __restrict__ vl,
                const int* __restrict__ fm, u16* __restrict__ out, int n)
{
  int i = (blockIdx.x * 256 + threadIdx.x) * 4;
  if (i >= n) return;
  float4 s4 = *(const float4*)(sc + i);
  float4 v4 = *(const float4*)(vl + i);
  int row = i >> 10;
  float neg = (1.f - (float)fm[row]) * (-1e30f);
  const float* sp = &s4.x; const float* vp = &v4.x;
  float r[4];
#pragma unroll
  for (int k = 0; k < 4; ++k) {
    float x = sp[k] + neg;
    r[k] = (1.f / (1.f + expf(-x))) * vp[k];
  }
  uint2 w;
  w.x = cvtpk(r[0], r[1]);
  w.y = cvtpk(r[2], r[3]);
  *(uint2*)(out + i) = w;
}

// ---------------- driver ----------------
extern "C" void kernel_launch(void* const* d_in, const int* in_sizes, int n_in,
                              void* d_out, int out_size, void* d_ws, size_t ws_size,
                              hipStream_t stream)
{
  (void)in_sizes; (void)n_in; (void)out_size; (void)ws_size;
  const float* from = (const float*)d_in[0];
  const float* to_t = (const float*)d_in[1];
  const float* ln1g = (const float*)d_in[2];
  const float* ln1b = (const float*)d_in[3];
  const float* lntg = (const float*)d_in[4];
  const float* lntb = (const float*)d_in[5];
  const float* ln2g = (const float*)d_in[6];
  const float* ln2b = (const float*)d_in[7];
  const int* fmask = (const int*)d_in[38];
  const int* tmask = (const int*)d_in[39];

  char* ws = (char*)d_ws;
  const size_t MB = 1ull << 20;
  auto WT = [&](int i) { return (u16*)(ws + (size_t)i * 2 * MB); };   // 0..28MB
  u16*   xbf    = (u16*)(ws + 28 * MB);
  u16*   tbf    = (u16*)(ws + 36 * MB);
  u16*   qh     = (u16*)(ws + 44 * MB);
  u16*   fkh    = (u16*)(ws + 52 * MB);
  u16*   fvt    = (u16*)(ws + 60 * MB);
  u16*   tkh    = (u16*)(ws + 68 * MB);
  u16*   tvt    = (u16*)(ws + 76 * MB);
  u16*   sctx   = (u16*)(ws + 84 * MB);
  u16*   xctx   = (u16*)(ws + 92 * MB);
  // temporally-disjoint reuse:
  float* fkadd  = (float*)(ws + 36 * MB);       // after tbf is dead
  float* tkadd  = fkadd + 4096;
  u16*   svb    = (u16*)(ws + 44 * MB);
  u16*   xvb    = (u16*)(ws + 52 * MB);
  u16*   sgb    = (u16*)(ws + 60 * MB);
  u16*   xgb    = (u16*)(ws + 68 * MB);
  u16*   gated  = (u16*)(ws + 76 * MB);
  u16*   sumbf  = (u16*)(ws + 92 * MB);
  float* scores = (float*)(ws + 44 * MB);       // 16MB
  float* values = (float*)(ws + 60 * MB);       // 16MB
  u16*   abf    = (u16*)(ws + 76 * MB);
  float* resid  = (float*)(ws + 84 * MB);       // 16MB
  u16*   lnr    = (u16*)(ws + 28 * MB);

  // weight order: contiguous groups for merged-N GEMMs
  W14 wsrc;
  const int widx[14] = {8, 10, 12, 14, 16, 18, 20, 22, 24, 26, 28, 31, 34, 36};
  for (int i = 0; i < 14; ++i) wsrc.p[i] = (const float*)d_in[widx[i]];
  wconv<<<dim3(16, 16, 14), dim3(64, 4), 0, stream>>>(wsrc, WT(0));

  ln_bf16<<<8192, 256, 0, stream>>>(from, ln1g, ln1b, xbf, to_t, lntg, lntb, tbf, 4096);

  const int M = 4096, Kd = 1024;
  GOut z{};
  GProb pz{};  // dummy for non-batched launches

  // G_A: x -> [Q | fK | fV], N=3072
  {
    GProb p{xbf, WT(0), {
      {qh,  (const float*)d_in[9],  nullptr, nullptr, 1.f, QSCALE, 1},
      {fkh, (const float*)d_in[11], nullptr, nullptr, 1.f, 1.f,    1},
      {fvt, (const float*)d_in[13], nullptr, nullptr, 1.f, 1.f,    2}}};
    gemm_bt<<<dim3(24, 32, 1), 256, 0, stream>>>(p, pz, M, Kd);
  }
  // G_B: t -> [tK | tV], N=2048
  {
    GProb p{tbf, WT(3), {
      {tkh, (const float*)d_in[15], nullptr, nullptr, 1.f, 1.f, 1},
      {tvt, (const float*)d_in[17], nullptr, nullptr, 1.f, 1.f, 2}, z}};
    gemm_bt<<<dim3(16, 32, 1), 256, 0, stream>>>(p, pz, M, Kd);
  }

  mk_maskf<<<16, 256, 0, stream>>>(fmask, tmask, fkadd, tkadd);

  attn_fused<<<1024, 256, 0, stream>>>(qh, fkh, fvt, fmask, fkadd, sctx);
  attn_fused<<<1024, 256, 0, stream>>>(qh, tkh, tvt, fmask, tkadd, xctx);

  // G_C: z-batched {sctx@Ws, xctx@Wx}
  {
    GProb p0{sctx, WT(5), {{svb, (const float*)d_in[19], nullptr, nullptr, 1.f, 1.f, 0}, z, z}};
    GProb p1{xctx, WT(6), {{xvb, (const float*)d_in[21], nullptr, nullptr, 1.f, 1.f, 0}, z, z}};
    gemm_bt<<<dim3(8, 32, 2), 256, 0, stream>>>(p0, p1, M, Kd);
  }
  // G_D: z-batched {svb@Wsg, xvb@Wxg}
  {
    GProb p0{svb, WT(7), {{sgb, (const float*)d_in[23], nullptr, nullptr, 1.f, 1.f, 0}, z, z}};
    GProb p1{xvb, WT(8), {{xgb, (const float*)d_in[25], nullptr, nullptr, 1.f, 1.f, 0}, z, z}};
    gemm_bt<<<dim3(8, 32, 2), 256, 0, stream>>>(p0, p1, M, Kd);
  }

  const int n = 4096 * 1024;
  ew_gated<<<n / (256 * 8), 256, 0, stream>>>(sgb, xvb, xgb, svb, gated, n);

  // G_E: gated @ Wg + bg, fused residual add with xbf -> sumbf (bf16)
  {
    GProb p{gated, WT(9), {{sumbf, (const float*)d_in[27], nullptr, xbf, 1.f, 1.f, 4}, z, z}};
    gemm_bt<<<dim3(8, 32, 1), 256, 0, stream>>>(p, pz, M, Kd);
  }
  // G_F: sumbf -> [scores | values], N=2048 (bias*2 + bilinear bias)
  {
    GProb p{sumbf, WT(10), {
      {scores, (const float*)d_in[29], (const float*)d_in[30], nullptr, 2.f, 1.f, 3},
      {values, (const float*)d_in[32], (const float*)d_in[33], nullptr, 2.f, 1.f, 3}, z}};
    gemm_bt<<<dim3(16, 32, 1), 256, 0, stream>>>(p, pz, M, Kd);
  }
  ew_attnout<<<n / (256 * 4), 256, 0, stream>>>(scores, values, fmask, abf, n);

  // G_G: abf @ Wd1 + bd1 + from -> resid (f32)
  {
    GProb p{abf, WT(12), {{resid, (const float*)d_in[35], nullptr, from, 1.f, 1.f, 3}, z, z}};
    gemm_bt<<<dim3(8, 32, 1), 256, 0, stream>>>(p, pz, M, Kd);
  }
  ln_bf16<<<4096, 256, 0, stream>>>(resid, ln2g, ln2b, lnr, resid, ln2g, ln2b, lnr, 4096);
  // G_H: lnr @ Wd2 + bd2 + resid -> out (f32)
  {
    GProb p{lnr, WT(13), {{d_out, (const float*)d_in[37], nullptr, resid, 1.f, 1.f, 3}, z, z}};
    gemm_bt<<<dim3(8, 32, 1), 256, 0, stream>>>(p, pz, M, Kd);
  }
}

// Round 3
// 543.878 us; speedup vs baseline: 1.1192x; 1.0269x over previous
//
#include <hip/hip_runtime.h>

typedef unsigned short u16;
typedef unsigned int   u32;

typedef __bf16 bf16x8 __attribute__((ext_vector_type(8)));
typedef float  f32x4  __attribute__((ext_vector_type(4)));

__device__ __forceinline__ float bf2f(u16 u) {
  union { u32 i; float f; } v; v.i = ((u32)u) << 16; return v.f;
}
__device__ __forceinline__ u16 f2bf(float f) {
  union { float f; u32 i; } v; v.f = f;
  u32 r = v.i + 0x7fffu + ((v.i >> 16) & 1u);   // RNE
  return (u16)(r >> 16);
}
__device__ __forceinline__ u32 cvtpk(float a, float b) {
  u32 r;
  asm("v_cvt_pk_bf16_f32 %0, %1, %2" : "=v"(r) : "v"(a), "v"(b));
  return r;
}

__device__ __forceinline__ f32x4 mfma16(bf16x8 a, bf16x8 b, f32x4 c) {
  return __builtin_amdgcn_mfma_f32_16x16x32_bf16(a, b, c, 0, 0, 0);
}

#define GLOAD_LDS16(gsrc, ldst) \
  __builtin_amdgcn_global_load_lds((const __attribute__((address_space(1))) void*)(gsrc), \
                                   (__attribute__((address_space(3))) void*)(ldst), 16, 0, 0)

// 0.125 * log2(e): folded into Q so softmax can use exp2
#define QSCALE 0.18033688011112042f

// ---------------- merged weight convert: Wt[n][k] = bf16(W[k][n]) ----------------
struct W14 { const float* p[14]; };

__global__ __launch_bounds__(256)
void wconv(W14 srcs, u16* __restrict__ base)
{
  __shared__ float tile[64][65];
  const int tx = threadIdx.x;           // 0..63
  const int ty = threadIdx.y;           // 0..3
  const int n0 = blockIdx.x * 64;
  const int k0 = blockIdx.y * 64;
  const float* W = srcs.p[blockIdx.z];
  u16* Wt = base + ((size_t)blockIdx.z << 20);
#pragma unroll
  for (int j = 0; j < 16; ++j) {
    int k = ty + j * 4;
    tile[k][tx] = W[(size_t)(k0 + k) * 1024 + n0 + tx];
  }
  __syncthreads();
  const int kp = tx & 31;               // k-pair index
  const int nx = (tx >> 5) * 4;         // extra n offset
#pragma unroll
  for (int j = 0; j < 8; ++j) {
    int n = ty + nx + j * 8;
    u32 w = (u32)f2bf(tile[2 * kp][n]) | ((u32)f2bf(tile[2 * kp + 1][n]) << 16);
    ((u32*)(Wt + (size_t)(n0 + n) * 1024 + k0))[kp] = w;
  }
}

// ---------------- LayerNorm (row = 1024) -> bf16, dual source ----------------
__global__ __launch_bounds__(256)
void ln_bf16(const float* __restrict__ in0, const float* __restrict__ g0,
             const float* __restrict__ b0, u16* __restrict__ out0,
             const float* __restrict__ in1, const float* __restrict__ g1,
             const float* __restrict__ b1, u16* __restrict__ out1, int split)
{
  int row = blockIdx.x;
  const float *in, *gw, *bw; u16* out;
  if (row < split) { in = in0; gw = g0; bw = b0; out = out0; }
  else             { in = in1; gw = g1; bw = b1; out = out1; row -= split; }
  const int t = threadIdx.x;
  const float4 v = ((const float4*)(in + (size_t)row * 1024))[t];
  float s  = v.x + v.y + v.z + v.w;
  float sq = v.x*v.x + v.y*v.y + v.z*v.z + v.w*v.w;
#pragma unroll
  for (int o = 32; o >= 1; o >>= 1) {
    s  += __shfl_xor(s, o);
    sq += __shfl_xor(sq, o);
  }
  __shared__ float red[8];
  const int wv = t >> 6;
  if ((t & 63) == 0) { red[wv] = s; red[4 + wv] = sq; }
  __syncthreads();
  s  = red[0] + red[1] + red[2] + red[3];
  sq = red[4] + red[5] + red[6] + red[7];
  const float mean = s * (1.f / 1024.f);
  const float var  = sq * (1.f / 1024.f) - mean * mean;
  const float rstd = rsqrtf(var + 1e-6f);
  const float4 g4 = ((const float4*)gw)[t];
  const float4 b4 = ((const float4*)bw)[t];
  uint2 w;
  w.x = cvtpk((v.x - mean) * rstd * g4.x + b4.x, (v.y - mean) * rstd * g4.y + b4.y);
  w.y = cvtpk((v.z - mean) * rstd * g4.z + b4.z, (v.w - mean) * rstd * g4.w + b4.w);
  ((uint2*)(out + (size_t)row * 1024))[t] = w;
}

// ---------------- GEMM: C = A[M,K](bf16) @ Bt[N,K](bf16)^T ----------------
// mode 0: bf16 row-major; 1: bf16 [B,H,L,HD]; 3: f32 (+f32 res);
// 4: bf16 (+bf16 res); 5: V-transposed — A=weight rows, Bt=activation rows,
//    out[((b*16+h)*64+hd)*512 + l], bias indexed by ROW.
struct GOut  { void* ptr; const float* bias; const void* res; float oscale; int mode; };
struct GProb { const u16* A; const u16* Bt; GOut od[2]; int odshift; };

__global__ __launch_bounds__(256)
void gemm_bt(GProb P0, GProb P1, int M, int K)
{
  const GProb pr = blockIdx.z ? P1 : P0;
  __shared__ u16 As[128 * 64];
  __shared__ u16 Bs[128 * 64];
  const int t    = threadIdx.x;
  const int lane = t & 63;
  const int wave = t >> 6;
  const int qi   = lane & 15;
  const int g    = lane >> 4;
  // XCD row-strip swizzle: each XCD gets a contiguous nid chunk, bx fastest
  const int GX   = gridDim.x;
  const int flat = blockIdx.x + GX * blockIdx.y;
  const int cpx  = (GX * gridDim.y) >> 3;
  const int nid  = (flat & 7) * cpx + (flat >> 3);
  const int bx   = nid % GX;
  const int by   = nid / GX;
  const int row0 = by * 128;
  const int col0 = bx * 128;
  const int wrow = (wave >> 1) * 64;
  const int wcol = (wave & 1) * 64;

  f32x4 acc[4][4] = {};

  const int srow  = lane >> 3;
  const int skseg = (lane & 7) * 8;
  const u16* A  = pr.A;
  const u16* Bt = pr.Bt;

  for (int kt = 0; kt < K; kt += 64) {
    __syncthreads();
#pragma unroll
    for (int i = 0; i < 8; ++i) {
      int chunk = wave * 8 + i;
      int c = chunk & 15;
      int r = c * 8 + srow;
      if (chunk < 16) {
        GLOAD_LDS16(A  + (size_t)(row0 + r) * K + kt + skseg, As + c * 512);
      } else {
        GLOAD_LDS16(Bt + (size_t)(col0 + r) * K + kt + skseg, Bs + c * 512);
      }
    }
    __syncthreads();
#pragma unroll
    for (int kk = 0; kk < 2; ++kk) {
      bf16x8 af[4], bfv[4];
#pragma unroll
      for (int m = 0; m < 4; ++m)
        af[m] = *(const bf16x8*)(As + (wrow + m * 16 + qi) * 64 + kk * 32 + g * 8);
#pragma unroll
      for (int n = 0; n < 4; ++n)
        bfv[n] = *(const bf16x8*)(Bs + (wcol + n * 16 + qi) * 64 + kk * 32 + g * 8);
#pragma unroll
      for (int m = 0; m < 4; ++m)
#pragma unroll
        for (int n = 0; n < 4; ++n)
          acc[m][n] = mfma16(af[m], bfv[n], acc[m][n]);
    }
  }

  const GOut od = pr.od[bx >> pr.odshift];
  const int cbase = (bx & ((1 << pr.odshift) - 1)) * 128 + wcol;
#pragma unroll
  for (int n = 0; n < 4; ++n) {
    int coll = cbase + n * 16 + qi;
    float badd = 0.f;
    if (od.mode != 5 && od.bias) badd = od.bias[coll];
#pragma unroll
    for (int m = 0; m < 4; ++m) {
#pragma unroll
      for (int j = 0; j < 4; ++j) {
        int row = row0 + wrow + m * 16 + g * 4 + j;
        float v = (acc[m][n][j] + badd) * od.oscale;
        if (od.mode == 0) {
          ((u16*)od.ptr)[(size_t)row * 1024 + coll] = f2bf(v);
        } else if (od.mode == 1) {
          int bb = row >> 9, l = row & 511, hh = coll >> 6, hd = coll & 63;
          ((u16*)od.ptr)[(((size_t)(bb * 16 + hh) * 512) + l) * 64 + hd] = f2bf(v);
        } else if (od.mode == 5) {
          float vb = v + od.bias[row];   // bias per output channel = row
          int hh = row >> 6, hd = row & 63, bb = coll >> 9, l = coll & 511;
          ((u16*)od.ptr)[(((size_t)(bb * 16 + hh) * 64) + hd) * 512 + l] = f2bf(vb);
        } else if (od.mode == 3) {
          float o = v;
          if (od.res) o += ((const float*)od.res)[(size_t)row * 1024 + coll];
          ((float*)od.ptr)[(size_t)row * 1024 + coll] = o;
        } else {
          float o = v + bf2f(((const u16*)od.res)[(size_t)row * 1024 + coll]);
          ((u16*)od.ptr)[(size_t)row * 1024 + coll] = f2bf(o);
        }
      }
    }
  }
}

// ---------------- fused bilinear: abf = sigmoid(A@W1+2b1+bl1+mask) * (A@W2+2b2+bl2) ----
__global__ __launch_bounds__(256)
void gemm_bilinear(const u16* __restrict__ A, const u16* __restrict__ Bt1,
                   const u16* __restrict__ Bt2,
                   const float* __restrict__ b1v, const float* __restrict__ bl1v,
                   const float* __restrict__ b2v, const float* __restrict__ bl2v,
                   const int* __restrict__ fm, u16* __restrict__ out, int K)
{
  __shared__ u16 As[128 * 64];
  __shared__ u16 B1s[128 * 64];
  __shared__ u16 B2s[128 * 64];
  const int t    = threadIdx.x;
  const int lane = t & 63;
  const int wave = t >> 6;
  const int qi   = lane & 15;
  const int g    = lane >> 4;
  const int GX   = gridDim.x;
  const int flat = blockIdx.x + GX * blockIdx.y;
  const int cpx  = (GX * gridDim.y) >> 3;
  const int nid  = (flat & 7) * cpx + (flat >> 3);
  const int bx   = nid % GX;
  const int by   = nid / GX;
  const int row0 = by * 128;
  const int col0 = bx * 128;
  const int wrow = (wave >> 1) * 64;
  const int wcol = (wave & 1) * 64;

  f32x4 accS[4][4] = {};
  f32x4 accV[4][4] = {};

  const int srow  = lane >> 3;
  const int skseg = (lane & 7) * 8;

  for (int kt = 0; kt < K; kt += 64) {
    __syncthreads();
#pragma unroll
    for (int i = 0; i < 12; ++i) {
      int c2 = wave * 12 + i;           // 0..47
      int buf = c2 >> 4;                // 0..2
      int c = c2 & 15;
      int r = c * 8 + srow;
      if (buf == 0) {
        GLOAD_LDS16(A   + (size_t)(row0 + r) * K + kt + skseg, As  + c * 512);
      } else if (buf == 1) {
        GLOAD_LDS16(Bt1 + (size_t)(col0 + r) * K + kt + skseg, B1s + c * 512);
      } else {
        GLOAD_LDS16(Bt2 + (size_t)(col0 + r) * K + kt + skseg, B2s + c * 512);
      }
    }
    __syncthreads();
#pragma unroll
    for (int kk = 0; kk < 2; ++kk) {
      bf16x8 af[4], bf1[4], bf2[4];
#pragma unroll
      for (int m = 0; m < 4; ++m)
        af[m] = *(const bf16x8*)(As + (wrow + m * 16 + qi) * 64 + kk * 32 + g * 8);
#pragma unroll
      for (int n = 0; n < 4; ++n) {
        bf1[n] = *(const bf16x8*)(B1s + (wcol + n * 16 + qi) * 64 + kk * 32 + g * 8);
        bf2[n] = *(const bf16x8*)(B2s + (wcol + n * 16 + qi) * 64 + kk * 32 + g * 8);
      }
#pragma unroll
      for (int m = 0; m < 4; ++m)
#pragma unroll
        for (int n = 0; n < 4; ++n) {
          accS[m][n] = mfma16(af[m], bf1[n], accS[m][n]);
          accV[m][n] = mfma16(af[m], bf2[n], accV[m][n]);
        }
    }
  }

#pragma unroll
  for (int n = 0; n < 4; ++n) {
    int coll = col0 + wcol + n * 16 + qi;
    float badd1 = b1v[coll] * 2.f + bl1v[coll];
    float badd2 = b2v[coll] * 2.f + bl2v[coll];
#pragma unroll
    for (int m = 0; m < 4; ++m) {
#pragma unroll
      for (int j = 0; j < 4; ++j) {
        int row = row0 + wrow + m * 16 + g * 4 + j;
        float neg = fm[row] ? 0.f : -1e30f;
        float sc = accS[m][n][j] + badd1 + neg;
        float sig = 1.f / (1.f + expf(-sc));
        float vv = accV[m][n][j] + badd2;
        ((u16*)out)[(size_t)row * 1024 + coll] = f2bf(sig * vv);
      }
    }
  }
}

// ---------------- fused flash attention ----------------
// Q (pre-scaled by QSCALE), K: [B,H,L,64] bf16; Vt: [B,H,64,T] bf16
__global__ __launch_bounds__(256)
void attn_fused(const u16* __restrict__ Q, const u16* __restrict__ Kh,
                const u16* __restrict__ Vt, const int* __restrict__ qmask,
                const int* __restrict__ kmask, u16* __restrict__ ctx)
{
  const int T = 512, L = 512;
  const int lane = threadIdx.x & 63;
  const int wave = threadIdx.x >> 6;
  const int qi = lane & 15;
  const int g  = lane >> 4;
  // XCD-bijective remap: each XCD owns 16 whole bh (K/V set = 2MB, L2-resident)
  const int bid  = blockIdx.x;              // 0..1023
  const int iw   = bid >> 3;
  const int bh   = (bid & 7) * 16 + (iw & 15);
  const int qblk = iw >> 4;
  const int b  = bh >> 4;
  const int h  = bh & 15;
  const int q0 = qblk * 64 + wave * 16;

  __shared__ u16 Plds[4][16 * 72];          // per-wave P^T bounce, NO barriers needed
  u16* Pl = Plds[wave];

  const size_t qoff = ((size_t)bh * L + q0 + qi) * 64;
  const bf16x8 qf0 = *(const bf16x8*)(Q + qoff + g * 8);
  const bf16x8 qf1 = *(const bf16x8*)(Q + qoff + 32 + g * 8);

  const float qmv = (float)qmask[b * L + q0 + qi];
  const int* kmb = kmask + b * T;
  float mrun = -3.0e38f, lrun = 0.f;
  f32x4 of[4] = {};

  for (int kb = 0; kb < T; kb += 64) {
    f32x4 st[4] = {};
    __builtin_amdgcn_s_setprio(1);
#pragma unroll
    for (int s = 0; s < 4; ++s) {
      const size_t koff = ((size_t)bh * T + kb + s * 16 + qi) * 64;
      bf16x8 ka0 = *(const bf16x8*)(Kh + koff + g * 8);
      bf16x8 ka1 = *(const bf16x8*)(Kh + koff + 32 + g * 8);
      st[s] = mfma16(ka0, qf0, st[s]);      // St[key, q]
      st[s] = mfma16(ka1, qf1, st[s]);
    }
    __builtin_amdgcn_s_setprio(0);
    float pv[16];
    float tmax = -3.0e38f;
#pragma unroll
    for (int s = 0; s < 4; ++s) {
      int4 km4 = *(const int4*)(kmb + kb + s * 16 + g * 4);
      const int* kp = &km4.x;
#pragma unroll
      for (int j = 0; j < 4; ++j) {
        float sv = (st[s][j] + (kp[j] ? 0.f : -1e30f)) * qmv;  // qmv==0 -> uniform row
        pv[s * 4 + j] = sv;
        tmax = fmaxf(tmax, sv);
      }
    }
    tmax = fmaxf(tmax, __shfl_xor(tmax, 16));
    tmax = fmaxf(tmax, __shfl_xor(tmax, 32));
    const float mnew = fmaxf(mrun, tmax);
    const float corr = exp2f(mrun - mnew);
    float tsum = 0.f;
#pragma unroll
    for (int i = 0; i < 16; ++i) {
      float p = exp2f(pv[i] - mnew);
      pv[i] = p;
      tsum += p;
    }
    tsum += __shfl_xor(tsum, 16);
    tsum += __shfl_xor(tsum, 32);
    lrun = lrun * corr + tsum;
    mrun = mnew;
    // write P^T -> per-wave LDS as [q][key_local]
#pragma unroll
    for (int s = 0; s < 4; ++s) {
      uint2 w;
      w.x = cvtpk(pv[s * 4 + 0], pv[s * 4 + 1]);
      w.y = cvtpk(pv[s * 4 + 2], pv[s * 4 + 3]);
      *(uint2*)(Pl + qi * 72 + s * 16 + g * 4) = w;
    }
    float cj[4];
#pragma unroll
    for (int j = 0; j < 4; ++j) cj[j] = __shfl(corr, g * 4 + j);
    const bf16x8 pa0 = *(const bf16x8*)(Pl + qi * 72 + g * 8);
    const bf16x8 pa1 = *(const bf16x8*)(Pl + qi * 72 + 32 + g * 8);
    __builtin_amdgcn_s_setprio(1);
#pragma unroll
    for (int nf = 0; nf < 4; ++nf) {
      const size_t voff = ((size_t)bh * 64 + nf * 16 + qi) * (size_t)T + kb + g * 8;
      bf16x8 vb0 = *(const bf16x8*)(Vt + voff);
      bf16x8 vb1 = *(const bf16x8*)(Vt + voff + 32);
      f32x4 o = of[nf];
#pragma unroll
      for (int j = 0; j < 4; ++j) o[j] *= cj[j];
      o = mfma16(pa0, vb0, o);
      of[nf] = mfma16(pa1, vb1, o);
    }
    __builtin_amdgcn_s_setprio(0);
  }
  const float linv = 1.f / lrun;
  float lj[4];
#pragma unroll
  for (int j = 0; j < 4; ++j) lj[j] = __shfl(linv, g * 4 + j);
#pragma unroll
  for (int nf = 0; nf < 4; ++nf) {
    int col = h * 64 + nf * 16 + qi;
#pragma unroll
    for (int j = 0; j < 4; ++j) {
      int row = q0 + g * 4 + j;
      ctx[((size_t)b * L + row) * 1024 + col] = f2bf(of[nf][j] * lj[j]);
    }
  }
}

// ---------------- elementwise ----------------
__global__ __launch_bounds__(256)
void ew_gated(const u16* __restrict__ sg, const u16* __restrict__ xv,
              const u16* __restrict__ xg, const u16* __restrict__ sv,
              u16* __restrict__ out, int n)
{
  int i = (blockIdx.x * 256 + threadIdx.x) * 8;
  if (i >= n) return;
  uint4 A = *(const uint4*)(sg + i);
  uint4 B = *(const uint4*)(xv + i);
  uint4 C = *(const uint4*)(xg + i);
  uint4 D = *(const uint4*)(sv + i);
  const u32* pa = (const u32*)&A; const u32* pb = (const u32*)&B;
  const u32* pc = (const u32*)&C; const u32* pd = (const u32*)&D;
  u32 r[4];
#pragma unroll
  for (int k = 0; k < 4; ++k) {
    float a0 = bf2f((u16)(pa[k] & 0xffffu)), a1 = bf2f((u16)(pa[k] >> 16));
    float b0 = bf2f((u16)(pb[k] & 0xffffu)), b1 = bf2f((u16)(pb[k] >> 16));
    float c0 = bf2f((u16)(pc[k] & 0xffffu)), c1 = bf2f((u16)(pc[k] >> 16));
    float d0 = bf2f((u16)(pd[k] & 0xffffu)), d1 = bf2f((u16)(pd[k] >> 16));
    r[k] = cvtpk(a0 * b0 + c0 * d0, a1 * b1 + c1 * d1);
  }
  *(uint4*)(out + i) = *(uint4*)r;
}

// ---------------- driver ----------------
extern "C" void kernel_launch(void* const* d_in, const int* in_sizes, int n_in,
                              void* d_out, int out_size, void* d_ws, size_t ws_size,
                              hipStream_t stream)
{
  (void)in_sizes; (void)n_in; (void)out_size; (void)ws_size;
  const float* from = (const float*)d_in[0];
  const float* to_t = (const float*)d_in[1];
  const float* ln1g = (const float*)d_in[2];
  const float* ln1b = (const float*)d_in[3];
  const float* lntg = (const float*)d_in[4];
  const float* lntb = (const float*)d_in[5];
  const float* ln2g = (const float*)d_in[6];
  const float* ln2b = (const float*)d_in[7];
  const int* fmask = (const int*)d_in[38];
  const int* tmask = (const int*)d_in[39];

  char* ws = (char*)d_ws;
  const size_t MB = 1ull << 20;
  auto WT = [&](int i) { return (u16*)(ws + (size_t)i * 2 * MB); };   // 0..28MB
  u16*   xbf    = (u16*)(ws + 28 * MB);
  u16*   tbf    = (u16*)(ws + 36 * MB);
  u16*   qh     = (u16*)(ws + 44 * MB);
  u16*   fkh    = (u16*)(ws + 52 * MB);
  u16*   fvt    = (u16*)(ws + 60 * MB);
  u16*   tkh    = (u16*)(ws + 68 * MB);
  u16*   tvt    = (u16*)(ws + 76 * MB);
  u16*   sctx   = (u16*)(ws + 84 * MB);
  u16*   xctx   = (u16*)(ws + 92 * MB);
  // temporally-disjoint reuse:
  u16*   svb    = (u16*)(ws + 44 * MB);
  u16*   xvb    = (u16*)(ws + 52 * MB);
  u16*   sgb    = (u16*)(ws + 60 * MB);
  u16*   xgb    = (u16*)(ws + 68 * MB);
  u16*   gated  = (u16*)(ws + 76 * MB);
  u16*   sumbf  = (u16*)(ws + 92 * MB);
  u16*   abf    = (u16*)(ws + 52 * MB);         // xvb dead after ew_gated
  float* resid  = (float*)(ws + 60 * MB);       // 16MB over sgb/xgb (dead)
  u16*   lnr    = (u16*)(ws + 44 * MB);         // svb dead

  W14 wsrc;
  const int widx[14] = {8, 10, 12, 14, 16, 18, 20, 22, 24, 26, 28, 31, 34, 36};
  for (int i = 0; i < 14; ++i) wsrc.p[i] = (const float*)d_in[widx[i]];
  wconv<<<dim3(16, 16, 14), dim3(64, 4), 0, stream>>>(wsrc, WT(0));

  ln_bf16<<<8192, 256, 0, stream>>>(from, ln1g, ln1b, xbf, to_t, lntg, lntb, tbf, 4096);

  const int M = 4096, Kd = 1024;
  GOut z{};
  GProb pz{};

  // G_A: x -> [Q | fK], N=2048
  {
    GProb p{xbf, WT(0), {
      {qh,  (const float*)d_in[9],  nullptr, QSCALE, 1},
      {fkh, (const float*)d_in[11], nullptr, 1.f,    1}}, 3};
    gemm_bt<<<dim3(16, 32, 1), 256, 0, stream>>>(p, pz, M, Kd);
  }
  // G_B: t -> tK, N=1024
  {
    GProb p{tbf, WT(3), {{tkh, (const float*)d_in[15], nullptr, 1.f, 1}, z}, 3};
    gemm_bt<<<dim3(8, 32, 1), 256, 0, stream>>>(p, pz, M, Kd);
  }
  // G_V: z-batched V-transposed GEMMs (A = weight, Bt = activation)
  {
    GProb p0{WT(2), xbf, {{fvt, (const float*)d_in[13], nullptr, 1.f, 5}, z}, 5};
    GProb p1{WT(4), tbf, {{tvt, (const float*)d_in[17], nullptr, 1.f, 5}, z}, 5};
    gemm_bt<<<dim3(32, 8, 2), 256, 0, stream>>>(p0, p1, 1024, Kd);
  }

  attn_fused<<<1024, 256, 0, stream>>>(qh, fkh, fvt, fmask, fmask, sctx);
  attn_fused<<<1024, 256, 0, stream>>>(qh, tkh, tvt, fmask, tmask, xctx);

  // G_C: z-batched {sctx@Ws, xctx@Wx}
  {
    GProb p0{sctx, WT(5), {{svb, (const float*)d_in[19], nullptr, 1.f, 0}, z}, 3};
    GProb p1{xctx, WT(6), {{xvb, (const float*)d_in[21], nullptr, 1.f, 0}, z}, 3};
    gemm_bt<<<dim3(8, 32, 2), 256, 0, stream>>>(p0, p1, M, Kd);
  }
  // G_D: z-batched {svb@Wsg, xvb@Wxg}
  {
    GProb p0{svb, WT(7), {{sgb, (const float*)d_in[23], nullptr, 1.f, 0}, z}, 3};
    GProb p1{xvb, WT(8), {{xgb, (const float*)d_in[25], nullptr, 1.f, 0}, z}, 3};
    gemm_bt<<<dim3(8, 32, 2), 256, 0, stream>>>(p0, p1, M, Kd);
  }

  const int n = 4096 * 1024;
  ew_gated<<<n / (256 * 8), 256, 0, stream>>>(sgb, xvb, xgb, svb, gated, n);

  // G_E: gated @ Wg + bg, fused residual add with xbf -> sumbf (bf16)
  {
    GProb p{gated, WT(9), {{sumbf, (const float*)d_in[27], xbf, 1.f, 4}, z}, 3};
    gemm_bt<<<dim3(8, 32, 1), 256, 0, stream>>>(p, pz, M, Kd);
  }
  // bilinear: sumbf -> sigmoid(scores)*values -> abf (fuses G_F + ew_attnout)
  gemm_bilinear<<<dim3(8, 32), 256, 0, stream>>>(
      sumbf, WT(10), WT(11),
      (const float*)d_in[29], (const float*)d_in[30],
      (const float*)d_in[32], (const float*)d_in[33],
      fmask, abf, Kd);

  // G_G: abf @ Wd1 + bd1 + from -> resid (f32)
  {
    GProb p{abf, WT(12), {{resid, (const float*)d_in[35], from, 1.f, 3}, z}, 3};
    gemm_bt<<<dim3(8, 32, 1), 256, 0, stream>>>(p, pz, M, Kd);
  }
  ln_bf16<<<4096, 256, 0, stream>>>(resid, ln2g, ln2b, lnr, resid, ln2g, ln2b, lnr, 4096);
  // G_H: lnr @ Wd2 + bd2 + resid -> out (f32)
  {
    GProb p{lnr, WT(13), {{d_out, (const float*)d_in[37], resid, 1.f, 3}, z}, 3};
    gemm_bt<<<dim3(8, 32, 1), 256, 0, stream>>>(p, pz, M, Kd);
  }
}

// Round 4
// 514.402 us; speedup vs baseline: 1.1833x; 1.0573x over previous
//
#include <hip/hip_runtime.h>

typedef unsigned short u16;
typedef unsigned int   u32;

typedef __bf16 bf16x8 __attribute__((ext_vector_type(8)));
typedef float  f32x4  __attribute__((ext_vector_type(4)));

__device__ __forceinline__ float bf2f(u16 u) {
  union { u32 i; float f; } v; v.i = ((u32)u) << 16; return v.f;
}
__device__ __forceinline__ u16 f2bf(float f) {
  union { float f; u32 i; } v; v.f = f;
  u32 r = v.i + 0x7fffu + ((v.i >> 16) & 1u);   // RNE
  return (u16)(r >> 16);
}
__device__ __forceinline__ u32 cvtpk(float a, float b) {
  u32 r;
  asm("v_cvt_pk_bf16_f32 %0, %1, %2" : "=v"(r) : "v"(a), "v"(b));
  return r;
}

__device__ __forceinline__ f32x4 mfma16(bf16x8 a, bf16x8 b, f32x4 c) {
  return __builtin_amdgcn_mfma_f32_16x16x32_bf16(a, b, c, 0, 0, 0);
}

#define GLOAD_LDS16(gsrc, ldst) \
  __builtin_amdgcn_global_load_lds((const __attribute__((address_space(1))) void*)(gsrc), \
                                   (__attribute__((address_space(3))) void*)(ldst), 16, 0, 0)

// 0.125 * log2(e): folded into Q so softmax can use exp2
#define QSCALE 0.18033688011112042f

// ---------------- merged weight convert: Wt[n][k] = bf16(W[k][n]) ----------------
struct W14 { const float* p[14]; };

__global__ __launch_bounds__(256)
void wconv(W14 srcs, u16* __restrict__ base)
{
  __shared__ float tile[64][65];
  const int tx = threadIdx.x;           // 0..63
  const int ty = threadIdx.y;           // 0..3
  const int n0 = blockIdx.x * 64;
  const int k0 = blockIdx.y * 64;
  const float* W = srcs.p[blockIdx.z];
  u16* Wt = base + ((size_t)blockIdx.z << 20);
#pragma unroll
  for (int j = 0; j < 16; ++j) {
    int k = ty + j * 4;
    tile[k][tx] = W[(size_t)(k0 + k) * 1024 + n0 + tx];
  }
  __syncthreads();
  const int kp = tx & 31;               // k-pair index
  const int nx = (tx >> 5) * 4;         // extra n offset
#pragma unroll
  for (int j = 0; j < 8; ++j) {
    int n = ty + nx + j * 8;
    u32 w = (u32)f2bf(tile[2 * kp][n]) | ((u32)f2bf(tile[2 * kp + 1][n]) << 16);
    ((u32*)(Wt + (size_t)(n0 + n) * 1024 + k0))[kp] = w;
  }
}

// ---------------- LayerNorm (row = 1024) -> bf16, dual source ----------------
__global__ __launch_bounds__(256)
void ln_bf16(const float* __restrict__ in0, const float* __restrict__ g0,
             const float* __restrict__ b0, u16* __restrict__ out0,
             const float* __restrict__ in1, const float* __restrict__ g1,
             const float* __restrict__ b1, u16* __restrict__ out1, int split)
{
  int row = blockIdx.x;
  const float *in, *gw, *bw; u16* out;
  if (row < split) { in = in0; gw = g0; bw = b0; out = out0; }
  else             { in = in1; gw = g1; bw = b1; out = out1; row -= split; }
  const int t = threadIdx.x;
  const float4 v = ((const float4*)(in + (size_t)row * 1024))[t];
  float s  = v.x + v.y + v.z + v.w;
  float sq = v.x*v.x + v.y*v.y + v.z*v.z + v.w*v.w;
#pragma unroll
  for (int o = 32; o >= 1; o >>= 1) {
    s  += __shfl_xor(s, o);
    sq += __shfl_xor(sq, o);
  }
  __shared__ float red[8];
  const int wv = t >> 6;
  if ((t & 63) == 0) { red[wv] = s; red[4 + wv] = sq; }
  __syncthreads();
  s  = red[0] + red[1] + red[2] + red[3];
  sq = red[4] + red[5] + red[6] + red[7];
  const float mean = s * (1.f / 1024.f);
  const float var  = sq * (1.f / 1024.f) - mean * mean;
  const float rstd = rsqrtf(var + 1e-6f);
  const float4 g4 = ((const float4*)gw)[t];
  const float4 b4 = ((const float4*)bw)[t];
  uint2 w;
  w.x = cvtpk((v.x - mean) * rstd * g4.x + b4.x, (v.y - mean) * rstd * g4.y + b4.y);
  w.y = cvtpk((v.z - mean) * rstd * g4.z + b4.z, (v.w - mean) * rstd * g4.w + b4.w);
  ((uint2*)(out + (size_t)row * 1024))[t] = w;
}

// ---------------- segmented GEMM: C = A[M,K](bf16) @ Bt[N,K](bf16)^T ----------------
// modes: 0 bf16 row-major; 1 bf16 [B,H,L,HD]; 3 f32 (+f32 res); 4 bf16 (+bf16 res);
// 5 V-transposed (A=weight rows, Bt=activation rows), bias indexed by ROW.
struct GOut { void* ptr; const float* bias; const void* res; float oscale; int mode; };
struct Seg  { const u16* A; const u16* Bt; GOut od[2]; int odshift; int gx; int start; };
struct Segs { Seg s[4]; int total; };

template<int BM>
__global__ __launch_bounds__(256)
void gemm_multi(Segs S, int K)
{
  constexpr int nA = BM / 8;            // A chunks (8 rows x 64 k each)
  constexpr int PW = (nA + 16) / 4;     // chunks per wave
  constexpr int MF = BM / 32;           // m-fragments per wave
  __shared__ u16 As[BM * 64];
  __shared__ u16 Bs[128 * 64];
  const int t    = threadIdx.x;
  const int lane = t & 63;
  const int wave = t >> 6;
  const int qi   = lane & 15;
  const int g    = lane >> 4;
  const int cpx  = S.total >> 3;        // XCD swizzle (total % 8 == 0 by construction)
  const int flat = blockIdx.x;
  const int nid  = (flat & 7) * cpx + (flat >> 3);
  int si = 0;
  if (nid >= S.s[1].start) si = 1;
  if (nid >= S.s[2].start) si = 2;
  if (nid >= S.s[3].start) si = 3;
  const Seg sg = S.s[si];
  const int local = nid - sg.start;
  const int bx = local % sg.gx;
  const int by = local / sg.gx;
  const int row0 = by * BM;
  const int col0 = bx * 128;
  const int wrow = (wave >> 1) * (BM / 2);
  const int wcol = (wave & 1) * 64;

  f32x4 acc[MF][4] = {};

  const int srow  = lane >> 3;
  const int skseg = (lane & 7) * 8;
  const u16* A  = sg.A;
  const u16* Bt = sg.Bt;

  for (int kt = 0; kt < K; kt += 64) {
    __syncthreads();
#pragma unroll
    for (int i = 0; i < PW; ++i) {
      int chunk = wave * PW + i;
      if (chunk < nA) {
        GLOAD_LDS16(A  + (size_t)(row0 + chunk * 8 + srow) * K + kt + skseg, As + chunk * 512);
      } else {
        int cb = chunk - nA;
        GLOAD_LDS16(Bt + (size_t)(col0 + cb * 8 + srow) * K + kt + skseg, Bs + cb * 512);
      }
    }
    __syncthreads();
#pragma unroll
    for (int kk = 0; kk < 2; ++kk) {
      bf16x8 af[MF], bfv[4];
#pragma unroll
      for (int m = 0; m < MF; ++m)
        af[m] = *(const bf16x8*)(As + (wrow + m * 16 + qi) * 64 + kk * 32 + g * 8);
#pragma unroll
      for (int n = 0; n < 4; ++n)
        bfv[n] = *(const bf16x8*)(Bs + (wcol + n * 16 + qi) * 64 + kk * 32 + g * 8);
#pragma unroll
      for (int m = 0; m < MF; ++m)
#pragma unroll
        for (int n = 0; n < 4; ++n)
          acc[m][n] = mfma16(af[m], bfv[n], acc[m][n]);
    }
  }

  const GOut od = sg.od[bx >> sg.odshift];
  const int cbase = (bx & ((1 << sg.odshift) - 1)) * 128 + wcol;
#pragma unroll
  for (int n = 0; n < 4; ++n) {
    int coll = cbase + n * 16 + qi;
    float badd = 0.f;
    if (od.mode != 5 && od.bias) badd = od.bias[coll];
#pragma unroll
    for (int m = 0; m < MF; ++m) {
#pragma unroll
      for (int j = 0; j < 4; ++j) {
        int row = row0 + wrow + m * 16 + g * 4 + j;
        float v = (acc[m][n][j] + badd) * od.oscale;
        if (od.mode == 0) {
          ((u16*)od.ptr)[(size_t)row * 1024 + coll] = f2bf(v);
        } else if (od.mode == 1) {
          int bb = row >> 9, l = row & 511, hh = coll >> 6, hd = coll & 63;
          ((u16*)od.ptr)[(((size_t)(bb * 16 + hh) * 512) + l) * 64 + hd] = f2bf(v);
        } else if (od.mode == 5) {
          float vb = v + od.bias[row];
          int hh = row >> 6, hd = row & 63, bb = coll >> 9, l = coll & 511;
          ((u16*)od.ptr)[(((size_t)(bb * 16 + hh) * 64) + hd) * 512 + l] = f2bf(vb);
        } else if (od.mode == 3) {
          float o = v;
          if (od.res) o += ((const float*)od.res)[(size_t)row * 1024 + coll];
          ((float*)od.ptr)[(size_t)row * 1024 + coll] = o;
        } else {
          float o = v + bf2f(((const u16*)od.res)[(size_t)row * 1024 + coll]);
          ((u16*)od.ptr)[(size_t)row * 1024 + coll] = f2bf(o);
        }
      }
    }
  }
}

// ---------------- dual-A dual-B gate GEMM (fuses Wsg/Wxg GEMMs + ew_gated) --------
// accS = A1@B1t^T + bs1 ; accX = A2@B2t^T + bs2
// out  = accS * A2[r,c] + accX * A1[r,c]      (BM=64 tiles)
__global__ __launch_bounds__(256)
void gemm_dual_gate(const u16* __restrict__ A1, const u16* __restrict__ A2,
                    const u16* __restrict__ B1t, const u16* __restrict__ B2t,
                    const float* __restrict__ bs1, const float* __restrict__ bs2,
                    u16* __restrict__ out, int K)
{
  __shared__ u16 As1[64 * 64];
  __shared__ u16 As2[64 * 64];
  __shared__ u16 B1s[128 * 64];
  __shared__ u16 B2s[128 * 64];
  const int t    = threadIdx.x;
  const int lane = t & 63;
  const int wave = t >> 6;
  const int qi   = lane & 15;
  const int g    = lane >> 4;
  const int flat = blockIdx.x;                  // 512 blocks
  const int nid  = (flat & 7) * 64 + (flat >> 3);
  const int bx   = nid & 7;
  const int by   = nid >> 3;
  const int row0 = by * 64;
  const int col0 = bx * 128;
  const int wrow = (wave >> 1) * 32;
  const int wcol = (wave & 1) * 64;

  f32x4 accS[2][4] = {};
  f32x4 accX[2][4] = {};

  const int srow  = lane >> 3;
  const int skseg = (lane & 7) * 8;

  for (int kt = 0; kt < K; kt += 64) {
    __syncthreads();
#pragma unroll
    for (int i = 0; i < 12; ++i) {
      int chunk = wave * 12 + i;                // 0..47
      if (chunk < 8) {
        GLOAD_LDS16(A1  + (size_t)(row0 + chunk * 8 + srow) * K + kt + skseg, As1 + chunk * 512);
      } else if (chunk < 16) {
        int c = chunk - 8;
        GLOAD_LDS16(A2  + (size_t)(row0 + c * 8 + srow) * K + kt + skseg, As2 + c * 512);
      } else if (chunk < 32) {
        int c = chunk - 16;
        GLOAD_LDS16(B1t + (size_t)(col0 + c * 8 + srow) * K + kt + skseg, B1s + c * 512);
      } else {
        int c = chunk - 32;
        GLOAD_LDS16(B2t + (size_t)(col0 + c * 8 + srow) * K + kt + skseg, B2s + c * 512);
      }
    }
    __syncthreads();
#pragma unroll
    for (int kk = 0; kk < 2; ++kk) {
      bf16x8 a1[2], a2[2], b1[4], b2[4];
#pragma unroll
      for (int m = 0; m < 2; ++m) {
        a1[m] = *(const bf16x8*)(As1 + (wrow + m * 16 + qi) * 64 + kk * 32 + g * 8);
        a2[m] = *(const bf16x8*)(As2 + (wrow + m * 16 + qi) * 64 + kk * 32 + g * 8);
      }
#pragma unroll
      for (int n = 0; n < 4; ++n) {
        b1[n] = *(const bf16x8*)(B1s + (wcol + n * 16 + qi) * 64 + kk * 32 + g * 8);
        b2[n] = *(const bf16x8*)(B2s + (wcol + n * 16 + qi) * 64 + kk * 32 + g * 8);
      }
#pragma unroll
      for (int m = 0; m < 2; ++m)
#pragma unroll
        for (int n = 0; n < 4; ++n) {
          accS[m][n] = mfma16(a1[m], b1[n], accS[m][n]);
          accX[m][n] = mfma16(a2[m], b2[n], accX[m][n]);
        }
    }
  }

#pragma unroll
  for (int n = 0; n < 4; ++n) {
    int coll = col0 + wcol + n * 16 + qi;
    float b1 = bs1[coll];
    float b2 = bs2[coll];
#pragma unroll
    for (int m = 0; m < 2; ++m) {
#pragma unroll
      for (int j = 0; j < 4; ++j) {
        int row = row0 + wrow + m * 16 + g * 4 + j;
        float sv = bf2f(A1[(size_t)row * 1024 + coll]);
        float xv = bf2f(A2[(size_t)row * 1024 + coll]);
        float o = (accS[m][n][j] + b1) * xv + (accX[m][n][j] + b2) * sv;
        out[(size_t)row * 1024 + coll] = f2bf(o);
      }
    }
  }
}

// ---------------- fused bilinear (BM=64): sigmoid(A@W1+2b1+bl1+mask)*(A@W2+2b2+bl2) ----
__global__ __launch_bounds__(256)
void gemm_bilinear(const u16* __restrict__ A, const u16* __restrict__ Bt1,
                   const u16* __restrict__ Bt2,
                   const float* __restrict__ b1v, const float* __restrict__ bl1v,
                   const float* __restrict__ b2v, const float* __restrict__ bl2v,
                   const int* __restrict__ fm, u16* __restrict__ out, int K)
{
  __shared__ u16 As[64 * 64];
  __shared__ u16 B1s[128 * 64];
  __shared__ u16 B2s[128 * 64];
  const int t    = threadIdx.x;
  const int lane = t & 63;
  const int wave = t >> 6;
  const int qi   = lane & 15;
  const int g    = lane >> 4;
  const int flat = blockIdx.x;                  // 512 blocks
  const int nid  = (flat & 7) * 64 + (flat >> 3);
  const int bx   = nid & 7;
  const int by   = nid >> 3;
  const int row0 = by * 64;
  const int col0 = bx * 128;
  const int wrow = (wave >> 1) * 32;
  const int wcol = (wave & 1) * 64;

  f32x4 accS[2][4] = {};
  f32x4 accV[2][4] = {};

  const int srow  = lane >> 3;
  const int skseg = (lane & 7) * 8;

  for (int kt = 0; kt < K; kt += 64) {
    __syncthreads();
#pragma unroll
    for (int i = 0; i < 10; ++i) {
      int chunk = wave * 10 + i;                // 0..39
      if (chunk < 8) {
        GLOAD_LDS16(A   + (size_t)(row0 + chunk * 8 + srow) * K + kt + skseg, As + chunk * 512);
      } else if (chunk < 24) {
        int c = chunk - 8;
        GLOAD_LDS16(Bt1 + (size_t)(col0 + c * 8 + srow) * K + kt + skseg, B1s + c * 512);
      } else {
        int c = chunk - 24;
        GLOAD_LDS16(Bt2 + (size_t)(col0 + c * 8 + srow) * K + kt + skseg, B2s + c * 512);
      }
    }
    __syncthreads();
#pragma unroll
    for (int kk = 0; kk < 2; ++kk) {
      bf16x8 af[2], bf1[4], bf2[4];
#pragma unroll
      for (int m = 0; m < 2; ++m)
        af[m] = *(const bf16x8*)(As + (wrow + m * 16 + qi) * 64 + kk * 32 + g * 8);
#pragma unroll
      for (int n = 0; n < 4; ++n) {
        bf1[n] = *(const bf16x8*)(B1s + (wcol + n * 16 + qi) * 64 + kk * 32 + g * 8);
        bf2[n] = *(const bf16x8*)(B2s + (wcol + n * 16 + qi) * 64 + kk * 32 + g * 8);
      }
#pragma unroll
      for (int m = 0; m < 2; ++m)
#pragma unroll
        for (int n = 0; n < 4; ++n) {
          accS[m][n] = mfma16(af[m], bf1[n], accS[m][n]);
          accV[m][n] = mfma16(af[m], bf2[n], accV[m][n]);
        }
    }
  }

#pragma unroll
  for (int n = 0; n < 4; ++n) {
    int coll = col0 + wcol + n * 16 + qi;
    float badd1 = b1v[coll] * 2.f + bl1v[coll];
    float badd2 = b2v[coll] * 2.f + bl2v[coll];
#pragma unroll
    for (int m = 0; m < 2; ++m) {
#pragma unroll
      for (int j = 0; j < 4; ++j) {
        int row = row0 + wrow + m * 16 + g * 4 + j;
        float neg = fm[row] ? 0.f : -1e30f;
        float sc = accS[m][n][j] + badd1 + neg;
        float sig = 1.f / (1.f + expf(-sc));
        float vv = accV[m][n][j] + badd2;
        out[(size_t)row * 1024 + coll] = f2bf(sig * vv);
      }
    }
  }
}

// ---------------- fused flash attention (both attentions, KVBLK=128) ----------------
__global__ __launch_bounds__(256)
void attn_fused(const u16* __restrict__ Q,
                const u16* __restrict__ K0, const u16* __restrict__ V0,
                const u16* __restrict__ K1, const u16* __restrict__ V1,
                const int* __restrict__ qmask,
                const int* __restrict__ km0, const int* __restrict__ km1,
                u16* __restrict__ ctx0, u16* __restrict__ ctx1)
{
  const int T = 512, L = 512;
  const int lane = threadIdx.x & 63;
  const int wave = threadIdx.x >> 6;
  const int qi = lane & 15;
  const int g  = lane >> 4;
  const int bid = blockIdx.x;               // 0..2047
  const int z   = bid >> 10;                // attn selector (slowest -> temporal XCD locality)
  const int ib  = bid & 1023;
  const int iw  = ib >> 3;
  const int bh  = (ib & 7) * 16 + (iw & 15);
  const int qblk = iw >> 4;
  const int b  = bh >> 4;
  const int h  = bh & 15;
  const int q0 = qblk * 64 + wave * 16;

  const u16* Kh = z ? K1 : K0;
  const u16* Vt = z ? V1 : V0;
  const int* kmb = (z ? km1 : km0) + b * T;
  u16* ctx = z ? ctx1 : ctx0;

  __shared__ u16 Plds[4][16 * 136];         // per-wave P^T bounce; no barriers needed
  u16* Pl = Plds[wave];

  const size_t qoff = ((size_t)bh * L + q0 + qi) * 64;
  const bf16x8 qf0 = *(const bf16x8*)(Q + qoff + g * 8);
  const bf16x8 qf1 = *(const bf16x8*)(Q + qoff + 32 + g * 8);

  const float qmv = (float)qmask[b * L + q0 + qi];
  float mrun = -3.0e38f, lrun = 0.f;
  f32x4 of[4] = {};

  for (int kb = 0; kb < T; kb += 128) {     // 4 iterations
    f32x4 st[8];
    __builtin_amdgcn_s_setprio(1);
#pragma unroll
    for (int s = 0; s < 8; ++s) {
      const size_t koff = ((size_t)bh * T + kb + s * 16 + qi) * 64;
      bf16x8 ka0 = *(const bf16x8*)(Kh + koff + g * 8);
      bf16x8 ka1 = *(const bf16x8*)(Kh + koff + 32 + g * 8);
      f32x4 acc = {};
      acc = mfma16(ka0, qf0, acc);          // St[key, q]
      st[s] = mfma16(ka1, qf1, acc);
    }
    __builtin_amdgcn_s_setprio(0);
    float pv[32];
    float tmax = -3.0e38f;
#pragma unroll
    for (int s = 0; s < 8; ++s) {
      int4 km4 = *(const int4*)(kmb + kb + s * 16 + g * 4);
      const int* kp = &km4.x;
#pragma unroll
      for (int j = 0; j < 4; ++j) {
        float sv = (st[s][j] + (kp[j] ? 0.f : -1e30f)) * qmv;  // qmv==0 -> uniform row
        pv[s * 4 + j] = sv;
        tmax = fmaxf(tmax, sv);
      }
    }
    tmax = fmaxf(tmax, __shfl_xor(tmax, 16));
    tmax = fmaxf(tmax, __shfl_xor(tmax, 32));
    const float mnew = fmaxf(mrun, tmax);
    const float corr = exp2f(mrun - mnew);
    float tsum = 0.f;
#pragma unroll
    for (int i = 0; i < 32; ++i) {
      float p = exp2f(pv[i] - mnew);
      pv[i] = p;
      tsum += p;
    }
    tsum += __shfl_xor(tsum, 16);
    tsum += __shfl_xor(tsum, 32);
    lrun = lrun * corr + tsum;
    mrun = mnew;
    // P^T -> per-wave LDS [q][key_local]
#pragma unroll
    for (int s = 0; s < 8; ++s) {
      uint2 w;
      w.x = cvtpk(pv[s * 4 + 0], pv[s * 4 + 1]);
      w.y = cvtpk(pv[s * 4 + 2], pv[s * 4 + 3]);
      *(uint2*)(Pl + qi * 136 + s * 16 + g * 4) = w;
    }
    float cj[4];
#pragma unroll
    for (int j = 0; j < 4; ++j) cj[j] = __shfl(corr, g * 4 + j);
    bf16x8 pa[4];
#pragma unroll
    for (int ks = 0; ks < 4; ++ks)
      pa[ks] = *(const bf16x8*)(Pl + qi * 136 + ks * 32 + g * 8);
    __builtin_amdgcn_s_setprio(1);
#pragma unroll
    for (int nf = 0; nf < 4; ++nf) {
      f32x4 o = of[nf];
#pragma unroll
      for (int j = 0; j < 4; ++j) o[j] *= cj[j];
#pragma unroll
      for (int ks = 0; ks < 4; ++ks) {
        const size_t voff = ((size_t)bh * 64 + nf * 16 + qi) * (size_t)T + kb + ks * 32 + g * 8;
        bf16x8 vb = *(const bf16x8*)(Vt + voff);
        o = mfma16(pa[ks], vb, o);
      }
      of[nf] = o;
    }
    __builtin_amdgcn_s_setprio(0);
  }
  const float linv = 1.f / lrun;
  float lj[4];
#pragma unroll
  for (int j = 0; j < 4; ++j) lj[j] = __shfl(linv, g * 4 + j);
#pragma unroll
  for (int nf = 0; nf < 4; ++nf) {
    int col = h * 64 + nf * 16 + qi;
#pragma unroll
    for (int j = 0; j < 4; ++j) {
      int row = q0 + g * 4 + j;
      ctx[((size_t)b * L + row) * 1024 + col] = f2bf(of[nf][j] * lj[j]);
    }
  }
}

// ---------------- driver ----------------
extern "C" void kernel_launch(void* const* d_in, const int* in_sizes, int n_in,
                              void* d_out, int out_size, void* d_ws, size_t ws_size,
                              hipStream_t stream)
{
  (void)in_sizes; (void)n_in; (void)out_size; (void)ws_size;
  const float* from = (const float*)d_in[0];
  const float* to_t = (const float*)d_in[1];
  const float* ln1g = (const float*)d_in[2];
  const float* ln1b = (const float*)d_in[3];
  const float* lntg = (const float*)d_in[4];
  const float* lntb = (const float*)d_in[5];
  const float* ln2g = (const float*)d_in[6];
  const float* ln2b = (const float*)d_in[7];
  const int* fmask = (const int*)d_in[38];
  const int* tmask = (const int*)d_in[39];

  char* ws = (char*)d_ws;
  const size_t MB = 1ull << 20;
  auto WT = [&](int i) { return (u16*)(ws + (size_t)i * 2 * MB); };   // 0..28MB
  u16*   xbf    = (u16*)(ws + 28 * MB);
  u16*   tbf    = (u16*)(ws + 36 * MB);
  u16*   qh     = (u16*)(ws + 44 * MB);
  u16*   fkh    = (u16*)(ws + 52 * MB);
  u16*   fvt    = (u16*)(ws + 60 * MB);
  u16*   tkh    = (u16*)(ws + 68 * MB);
  u16*   tvt    = (u16*)(ws + 76 * MB);
  u16*   sctx   = (u16*)(ws + 84 * MB);
  u16*   xctx   = (u16*)(ws + 92 * MB);
  // temporally-disjoint reuse:
  u16*   svb    = (u16*)(ws + 44 * MB);
  u16*   xvb    = (u16*)(ws + 52 * MB);
  u16*   gated  = (u16*)(ws + 76 * MB);
  u16*   sumbf  = (u16*)(ws + 92 * MB);
  u16*   abf    = (u16*)(ws + 68 * MB);         // tkh dead after attn
  float* resid  = (float*)(ws + 60 * MB);       // 16MB (fvt dead)
  u16*   lnr    = (u16*)(ws + 84 * MB);         // sctx dead

  W14 wsrc;
  const int widx[14] = {8, 10, 12, 14, 16, 18, 20, 22, 24, 26, 28, 31, 34, 36};
  for (int i = 0; i < 14; ++i) wsrc.p[i] = (const float*)d_in[widx[i]];
  wconv<<<dim3(16, 16, 14), dim3(64, 4), 0, stream>>>(wsrc, WT(0));

  ln_bf16<<<8192, 256, 0, stream>>>(from, ln1g, ln1b, xbf, to_t, lntg, lntb, tbf, 4096);

  const int Kd = 1024;
  GOut z{};
  const int FAR = 0x7fffffff;

  // pre-attn: [Q|fK from x] + [tK from t] + [fV^T] + [tV^T]  (1280 blocks)
  {
    Segs S{};
    S.s[0] = {xbf, WT(0), {{qh,  (const float*)d_in[9],  nullptr, QSCALE, 1},
                           {fkh, (const float*)d_in[11], nullptr, 1.f,    1}}, 3, 16, 0};
    S.s[1] = {tbf, WT(3), {{tkh, (const float*)d_in[15], nullptr, 1.f, 1}, z}, 3, 8, 512};
    S.s[2] = {WT(2), xbf, {{fvt, (const float*)d_in[13], nullptr, 1.f, 5}, z}, 5, 32, 768};
    S.s[3] = {WT(4), tbf, {{tvt, (const float*)d_in[17], nullptr, 1.f, 5}, z}, 5, 32, 1024};
    S.total = 1280;
    gemm_multi<128><<<1280, 256, 0, stream>>>(S, Kd);
  }

  attn_fused<<<2048, 256, 0, stream>>>(qh, fkh, fvt, tkh, tvt, fmask, fmask, tmask, sctx, xctx);

  // G_C: {sctx@Ws -> svb, xctx@Wx -> xvb}  (1024 blocks, BM=64)
  {
    Segs S{};
    S.s[0] = {sctx, WT(5), {{svb, (const float*)d_in[19], nullptr, 1.f, 0}, z}, 3, 8, 0};
    S.s[1] = {xctx, WT(6), {{xvb, (const float*)d_in[21], nullptr, 1.f, 0}, z}, 3, 8, 512};
    S.s[2].start = FAR; S.s[3].start = FAR;
    S.total = 1024;
    gemm_multi<64><<<1024, 256, 0, stream>>>(S, Kd);
  }

  // dual gate: gated = (svb@Wsg+bsg)*xvb + (xvb@Wxg+bxg)*svb  (512 blocks)
  gemm_dual_gate<<<512, 256, 0, stream>>>(svb, xvb, WT(7), WT(8),
      (const float*)d_in[23], (const float*)d_in[25], gated, Kd);

  // G_E: gated @ Wg + bg + xbf -> sumbf (bf16)
  {
    Segs S{};
    S.s[0] = {gated, WT(9), {{sumbf, (const float*)d_in[27], xbf, 1.f, 4}, z}, 3, 8, 0};
    S.s[1].start = FAR; S.s[2].start = FAR; S.s[3].start = FAR;
    S.total = 512;
    gemm_multi<64><<<512, 256, 0, stream>>>(S, Kd);
  }

  // bilinear: sumbf -> sigmoid(scores)*values -> abf
  gemm_bilinear<<<512, 256, 0, stream>>>(
      sumbf, WT(10), WT(11),
      (const float*)d_in[29], (const float*)d_in[30],
      (const float*)d_in[32], (const float*)d_in[33],
      fmask, abf, Kd);

  // G_G: abf @ Wd1 + bd1 + from -> resid (f32)
  {
    Segs S{};
    S.s[0] = {abf, WT(12), {{resid, (const float*)d_in[35], from, 1.f, 3}, z}, 3, 8, 0};
    S.s[1].start = FAR; S.s[2].start = FAR; S.s[3].start = FAR;
    S.total = 512;
    gemm_multi<64><<<512, 256, 0, stream>>>(S, Kd);
  }

  ln_bf16<<<4096, 256, 0, stream>>>(resid, ln2g, ln2b, lnr, resid, ln2g, ln2b, lnr, 4096);

  // G_H: lnr @ Wd2 + bd2 + resid -> out (f32)
  {
    Segs S{};
    S.s[0] = {lnr, WT(13), {{d_out, (const float*)d_in[37], resid, 1.f, 3}, z}, 3, 8, 0};
    S.s[1].start = FAR; S.s[2].start = FAR; S.s[3].start = FAR;
    S.total = 512;
    gemm_multi<64><<<512, 256, 0, stream>>>(S, Kd);
  }
}